// Round 6
// baseline (5750.135 us; speedup 1.0000x reference)
//
#include <hip/hip_runtime.h>
#include <stdint.h>

// ---------------------------------------------------------------------------
// SpikeMLP (all fp32 I/O):
//   h = x @ w1^T            (16384,512)x(2048,512)^T -> (16384,2048)
//   spikes,rate = LIF(h)    scan over t (4 steps, rows grouped (b,t,s))
//   out = spikes @ w2^T     (16384,2048)x(512,2048)^T -> (16384,512)
//
// Numerics contract (DO NOT BREAK):
//   - GEMM1 (k1): per-element f32 sequential FMA over k=0..511 ascending,
//     one accumulator -> bit-exact match of the np reference's h.
//   - LIF: vv = __fmul_rn(0.95f, v); vv = __fadd_rn(vv, h); spike = vv > 1.
//   - GEMM2 is continuous in spikes {0,1} -> MFMA allowed (w2 hi+lo bf16).
//
// k1 (round 13): DMA staging + counted vmcnt (m97/m218 pattern).
//   Rounds 1/4/5 plateau at 390-414 us: VALU-staging + __syncthreads
//   (vmcnt-0 drain) is the structural binder. This round:
//   - One-time prep: xT[k][b][s][t] (33.5 MB) and w1T[k][h] (4 MB) so each
//     k-row of a block's A/B tile is 128 CONTIGUOUS floats -> global_load_lds
//     (16 B/lane, lane-linear dest) stages straight into [k][128] LDS.
//   - K-chunk 16, 2 buffer pairs (32 KB LDS = 5 blocks/CU), 8x8 micro,
//     __launch_bounds__(256,5) (staging regs freed; acc64 + ~25 live).
//   - Loop: issue(c+1) -> s_waitcnt vmcnt(4) -> s_barrier -> compute(c)
//     -> lgkm+s_barrier. vmcnt NEVER drains to 0 in the main loop.
//   - No skew needed: DMA writes are lane-linear; A-reads 16-lane broadcast
//     (4 distinct banks), B-reads optimal 2-sweep (the benign 2^23 counter).
//   Transposes are pure data movement: FMA order (k ascending) and LIF
//   unchanged -> bit-identical spikes. Legacy round-1 k1 kept as fallback
//   when ws < ~104 MB.
// ---------------------------------------------------------------------------

typedef __attribute__((ext_vector_type(8))) short short8;   // 8 bf16 = 16 B
typedef __attribute__((ext_vector_type(4))) float f32x4;

#define AS1 __attribute__((address_space(1)))
#define AS3 __attribute__((address_space(3)))

__device__ __forceinline__ void load_lds16(const void* g, void* l) {
  __builtin_amdgcn_global_load_lds((const AS1 void*)g, (AS3 void*)l, 16, 0, 0);
}

__device__ __forceinline__ unsigned short f2bf(float f) {
  union { float f; unsigned u; } un; un.f = f;
  unsigned r = un.u + 0x7FFF + ((un.u >> 16) & 1);   // RNE
  return (unsigned short)(r >> 16);
}
__device__ __forceinline__ float bf2f(unsigned short u) {
  union { unsigned u; float f; } un; un.u = ((unsigned)u) << 16; return un.f;
}

// ---------------------------------------------------------------------------
// K0: split w2 (fp32) into bf16 hi + lo.
// ---------------------------------------------------------------------------
__global__ __launch_bounds__(256) void k0_split(
    const float* __restrict__ w2, unsigned short* __restrict__ hi,
    unsigned short* __restrict__ lo)
{
  int i = (blockIdx.x * 256 + threadIdx.x) * 4;
  float4 w = *(const float4*)&w2[i];
  unsigned short h4[4], l4[4];
  float ws[4] = {w.x, w.y, w.z, w.w};
#pragma unroll
  for (int c = 0; c < 4; ++c) {
    unsigned short h = f2bf(ws[c]);
    h4[c] = h;
    l4[c] = f2bf(ws[c] - bf2f(h));
  }
  *(ushort4*)&hi[i] = *(const ushort4*)h4;
  *(ushort4*)&lo[i] = *(const ushort4*)l4;
}

// ---------------------------------------------------------------------------
// K0X: xT[((k*16+b)*256+s)*4 + t] = x[((b*4+t)*256+s)*512 + k]
// Per k, a k1-block's 128 A-rows (p = sl*4+t) become 128 contiguous floats.
// Grid 512 blocks: bx -> b = bx>>5, st = (bx>>3)&3, kt = bx&7. 256 thr.
// ---------------------------------------------------------------------------
__global__ __launch_bounds__(256) void k0x_xpose_x(
    const float* __restrict__ x, float* __restrict__ xT)
{
  __shared__ float tile4[64 * 256];   // [kl][sl*4+t], 64 KB

  const int tid = threadIdx.x;
  const int b  = blockIdx.x >> 5;
  const int st = (blockIdx.x >> 3) & 3;
  const int kt = blockIdx.x & 7;
  const int s0 = st * 64;
  const int k0 = kt * 64;

  const int sl = tid >> 2;            // 0..63
#pragma unroll
  for (int t = 0; t < 4; ++t) {
    const float* xrow = x + ((size_t)((b * 4 + t) * 256) + s0 + sl) * 512 + k0;
#pragma unroll
    for (int u = 0; u < 4; ++u) {
      const int klb = (tid & 3) * 4 + u * 16;
      float4 v = *(const float4*)&xrow[klb];
      tile4[(klb + 0) * 256 + sl * 4 + t] = v.x;
      tile4[(klb + 1) * 256 + sl * 4 + t] = v.y;
      tile4[(klb + 2) * 256 + sl * 4 + t] = v.z;
      tile4[(klb + 3) * 256 + sl * 4 + t] = v.w;
    }
  }
  __syncthreads();

#pragma unroll
  for (int w = 0; w < 16; ++w) {
    const int kl = w * 4 + (tid >> 6);
    const size_t g = (size_t)((k0 + kl) * 16 + b) * 1024 + s0 * 4 + (tid & 63) * 4;
    *(float4*)&xT[g] = *(const float4*)&tile4[kl * 256 + (tid & 63) * 4];
  }
}

// ---------------------------------------------------------------------------
// K0W: w1T[k][h] = w1[h][k].  Grid 256 blocks: ht = bx>>3, kt = bx&7.
// ---------------------------------------------------------------------------
__global__ __launch_bounds__(256) void k0w_xpose_w1(
    const float* __restrict__ w1, float* __restrict__ w1T)
{
  __shared__ float tile[64 * 68];

  const int tid = threadIdx.x;
  const int h0 = (blockIdx.x >> 3) * 64;
  const int k0 = (blockIdx.x & 7) * 64;

  const int hl = tid >> 2;
#pragma unroll
  for (int u = 0; u < 4; ++u) {
    const int klb = (tid & 3) * 4 + u * 16;
    float4 v = *(const float4*)&w1[(size_t)(h0 + hl) * 512 + k0 + klb];
    tile[(klb + 0) * 68 + hl] = v.x;
    tile[(klb + 1) * 68 + hl] = v.y;
    tile[(klb + 2) * 68 + hl] = v.z;
    tile[(klb + 3) * 68 + hl] = v.w;
  }
  __syncthreads();

#pragma unroll
  for (int it = 0; it < 16; ++it) {
    const int kl = it * 4 + (tid >> 6);
    w1T[(size_t)(k0 + kl) * 2048 + h0 + (tid & 63)] = tile[kl * 68 + (tid & 63)];
  }
}

// ---------------------------------------------------------------------------
// K1 (DMA): fused GEMM1 + thread-local LIF.  Tile 128x128 (p = sl*4+t),
// 256 thr, 8x8 micro, 5 waves/SIMD.  Grid (128,16).
// ---------------------------------------------------------------------------
#define K1_COMPUTE(SA, SB)                                                 \
  do {                                                                     \
    _Pragma("unroll")                                                      \
    for (int k = 0; k < 16; ++k) {                                         \
      float4 va0 = *(const float4*)&SA[ty * 8 + k * 128];                  \
      float4 va1 = *(const float4*)&SA[ty * 8 + 4 + k * 128];              \
      float4 vb0 = *(const float4*)&SB[tx * 4 + k * 128];                  \
      float4 vb1 = *(const float4*)&SB[tx * 4 + 64 + k * 128];             \
      float av[8] = {va0.x, va0.y, va0.z, va0.w,                           \
                     va1.x, va1.y, va1.z, va1.w};                          \
      float bv[8] = {vb0.x, vb0.y, vb0.z, vb0.w,                           \
                     vb1.x, vb1.y, vb1.z, vb1.w};                          \
      _Pragma("unroll")                                                    \
      for (int m = 0; m < 8; ++m)                                          \
        _Pragma("unroll")                                                  \
        for (int j = 0; j < 8; ++j)                                        \
          acc[m][j] = __builtin_fmaf(av[m], bv[j], acc[m][j]);             \
    }                                                                      \
  } while (0)

// issue one 16-k chunk: 4 global_load_lds (A lo/hi k-half, B lo/hi).
#define K1_ISSUE(CHUNK, DA, DB)                                            \
  do {                                                                     \
    const float* _sA = xT + (size_t)((CHUNK) * 16 + kk) * 16384 + aOff;    \
    const float* _sB = w1T + (size_t)((CHUNK) * 16 + kk) * 2048 + bOff;    \
    load_lds16(_sA,              (DA) + wuB);                              \
    load_lds16(_sA + 8 * 16384,  (DA) + wuB + 1024);                       \
    load_lds16(_sB,              (DB) + wuB);                              \
    load_lds16(_sB + 8 * 2048,   (DB) + wuB + 1024);                       \
  } while (0)

#define K1_W4B() asm volatile("s_waitcnt vmcnt(4)\ns_barrier" ::: "memory")
#define K1_W0B() asm volatile("s_waitcnt vmcnt(0)\ns_barrier" ::: "memory")
#define K1_LGB() asm volatile("s_waitcnt lgkmcnt(0)\ns_barrier" ::: "memory")

__global__ __launch_bounds__(256, 5) void k1_gemm_lif_dma(
    const float* __restrict__ xT,         // (512,16,256,4) transposed x
    const float* __restrict__ w1T,        // (512, 2048) transposed w1
    unsigned short* __restrict__ spikes,  // (16384, 2048) bf16 {0,1}
    unsigned* __restrict__ cnt_out)
{
  __shared__ float sA0[16 * 128];   // 8 KB each, 32 KB total
  __shared__ float sB0[16 * 128];
  __shared__ float sA1[16 * 128];
  __shared__ float sB1[16 * 128];

  const int tid = threadIdx.x;
  const int tx  = tid & 15;    // col group: cols tx*4..+3 and 64+tx*4..+3
  const int ty  = tid >> 4;    // s-pair index: sl = ty*2 + i

  const int bx = blockIdx.x;
  const int b  = bx >> 3;
  const int s0 = (bx & 7) * 32;
  const int h0 = blockIdx.y * 128;

  // DMA addressing: lane loads 16 B of k-row kk at p-quad (tid&31)*4.
  const int kk   = tid >> 5;                        // 0..7
  const int aOff = (b * 256 + s0) * 4 + (tid & 31) * 4;
  const int bOff = h0 + (tid & 31) * 4;
  const int wuB  = (tid >> 6) * 256;                // wave-uniform LDS base (floats)

  float acc[8][8];
#pragma unroll
  for (int m = 0; m < 8; ++m)
#pragma unroll
    for (int j = 0; j < 8; ++j) acc[m][j] = 0.0f;

  K1_ISSUE(0, sA0, sB0);

  for (int c = 0; c < 32; c += 2) {
    // ---- chunk c in buf0 ----
    K1_ISSUE(c + 1, sA1, sB1);
    K1_W4B();                       // chunk-c DMA done (4 newest stay in flight)
    K1_COMPUTE(sA0, sB0);
    K1_LGB();                       // close reads of buf0 before its next DMA
    // ---- chunk c+1 in buf1 ----
    if (c < 30) { K1_ISSUE(c + 2, sA0, sB0); K1_W4B(); }
    else        { K1_W0B(); }
    K1_COMPUTE(sA1, sB1);
    if (c < 30) K1_LGB();
  }

  // Epilogue: LIF. Thread owns all 4 t of its 2 s-rows -> local chain.
  unsigned cnt = 0;
#pragma unroll
  for (int i = 0; i < 2; ++i) {
    unsigned short sp[4][8];
#pragma unroll
    for (int j = 0; j < 8; ++j) {
      float v = 0.0f;
#pragma unroll
      for (int t = 0; t < 4; ++t) {
        float vv = __fadd_rn(__fmul_rn(0.95f, v), acc[i * 4 + t][j]);
        bool s = vv > 1.0f;                 // numpy op-for-op
        sp[t][j] = s ? (unsigned short)0x3F80 : (unsigned short)0;
        cnt += s ? 1u : 0u;
        v = s ? 0.0f : vv;
      }
    }
#pragma unroll
    for (int t = 0; t < 4; ++t) {
      size_t grow = ((size_t)(b * 4 + t) << 8) + s0 + ty * 2 + i;
      unsigned short* rowp = spikes + grow * 2048 + h0;
      ushort4 o0, o1;
      o0.x = sp[t][0]; o0.y = sp[t][1]; o0.z = sp[t][2]; o0.w = sp[t][3];
      o1.x = sp[t][4]; o1.y = sp[t][5]; o1.z = sp[t][6]; o1.w = sp[t][7];
      *(ushort4*)&rowp[tx * 4]      = o0;
      *(ushort4*)&rowp[64 + tx * 4] = o1;
    }
  }

#pragma unroll
  for (int off = 32; off; off >>= 1) cnt += __shfl_down(cnt, off);
  if ((tid & 63) == 0) atomicAdd(cnt_out, cnt);
}

// ---------------------------------------------------------------------------
// K1 legacy (round-1, 390 us): used when ws lacks room for xT/w1T.
// ---------------------------------------------------------------------------
#define L_KT 16
#define L_SA 176
#define L_SB 176

__global__ __launch_bounds__(256, 4) void k1_gemm_lif_legacy(
    const float* __restrict__ x,
    const float* __restrict__ w1,
    unsigned short* __restrict__ spikes,
    unsigned* __restrict__ cnt_out)
{
  __shared__ float sA[L_KT * L_SA];
  __shared__ float sB[L_KT * L_SB];

  const int tid = threadIdx.x;
  const int tx  = tid & 15;
  const int ty  = tid >> 4;

  const int bx = blockIdx.x;
  const int b  = bx >> 3;
  const int s0 = (bx & 7) * 32;
  const int h0 = blockIdx.y * 128;

  const int kg = tid & 3;
  const int u  = tid >> 2;

  float acc[8][8];
#pragma unroll
  for (int m = 0; m < 8; ++m)
#pragma unroll
    for (int j = 0; j < 8; ++j) acc[m][j] = 0.0f;

  const size_t growA0 = ((size_t)(b * 4 + (u & 3)) << 8) + s0 + (u >> 2);
  const size_t growA1 = growA0 + 16;
  const float* xA0 = x  + growA0 * 512 + kg * 4;
  const float* xA1 = x  + growA1 * 512 + kg * 4;
  const float* wB0 = w1 + (size_t)(h0 + u) * 512 + kg * 4;
  const float* wB1 = w1 + (size_t)(h0 + u + 64) * 512 + kg * 4;

  float* sAw = &sA[(4 * kg) * L_SA + u + 16 * kg];
  float* sBw = &sB[(4 * kg) * L_SB + u + 16 * kg];

  const float* sAr = &sA[ty * 8];
  const float* sBr = &sB[tx * 4];

  for (int k0 = 0; k0 < 512; k0 += L_KT) {
    float4 a0v = *(const float4*)(xA0 + k0);
    float4 a1v = *(const float4*)(xA1 + k0);
    float4 b0v = *(const float4*)(wB0 + k0);
    float4 b1v = *(const float4*)(wB1 + k0);

    __syncthreads();
    {
      float a0s[4] = {a0v.x, a0v.y, a0v.z, a0v.w};
      float a1s[4] = {a1v.x, a1v.y, a1v.z, a1v.w};
      float b0s[4] = {b0v.x, b0v.y, b0v.z, b0v.w};
      float b1s[4] = {b1v.x, b1v.y, b1v.z, b1v.w};
#pragma unroll
      for (int c = 0; c < 4; ++c) {
        sAw[c * L_SA]      = a0s[c];
        sAw[c * L_SA + 64] = a1s[c];
        sBw[c * L_SB]      = b0s[c];
        sBw[c * L_SB + 64] = b1s[c];
      }
    }
    __syncthreads();

#pragma unroll
    for (int k = 0; k < L_KT; ++k) {
      const int off = k * L_SA + 16 * (k >> 2);
      float4 va0 = *(const float4*)(sAr + off);
      float4 va1 = *(const float4*)(sAr + off + 4);
      float4 vb0 = *(const float4*)(sBr + off);
      float4 vb1 = *(const float4*)(sBr + off + 64);
      float av[8] = {va0.x, va0.y, va0.z, va0.w, va1.x, va1.y, va1.z, va1.w};
      float bv[8] = {vb0.x, vb0.y, vb0.z, vb0.w, vb1.x, vb1.y, vb1.z, vb1.w};
#pragma unroll
      for (int m = 0; m < 8; ++m)
#pragma unroll
        for (int j = 0; j < 8; ++j)
          acc[m][j] = __builtin_fmaf(av[m], bv[j], acc[m][j]);
    }
  }

  unsigned cnt = 0;
#pragma unroll
  for (int i = 0; i < 2; ++i) {
    unsigned short sp[4][8];
#pragma unroll
    for (int j = 0; j < 8; ++j) {
      float v = 0.0f;
#pragma unroll
      for (int t = 0; t < 4; ++t) {
        float vv = __fadd_rn(__fmul_rn(0.95f, v), acc[i * 4 + t][j]);
        bool s = vv > 1.0f;
        sp[t][j] = s ? (unsigned short)0x3F80 : (unsigned short)0;
        cnt += s ? 1u : 0u;
        v = s ? 0.0f : vv;
      }
    }
#pragma unroll
    for (int t = 0; t < 4; ++t) {
      size_t grow = ((size_t)(b * 4 + t) << 8) + s0 + ty * 2 + i;
      unsigned short* rowp = spikes + grow * 2048 + h0;
      ushort4 o0, o1;
      o0.x = sp[t][0]; o0.y = sp[t][1]; o0.z = sp[t][2]; o0.w = sp[t][3];
      o1.x = sp[t][4]; o1.y = sp[t][5]; o1.z = sp[t][6]; o1.w = sp[t][7];
      *(ushort4*)&rowp[tx * 4]      = o0;
      *(ushort4*)&rowp[64 + tx * 4] = o1;
    }
  }

#pragma unroll
  for (int off = 32; off; off >>= 1) cnt += __shfl_down(cnt, off);
  if ((tid & 63) == 0) atomicAdd(cnt_out, cnt);
}

// ---------------------------------------------------------------------------
// K2: out = spikes @ (w2_hi + w2_lo)^T via bf16 MFMA, fp32 accum.
// ---------------------------------------------------------------------------
__global__ __launch_bounds__(256, 2) void k2_gemm_mfma(
    const unsigned short* __restrict__ spikes,
    const unsigned short* __restrict__ w2h,
    const unsigned short* __restrict__ w2l,
    float* __restrict__ out)
{
  __shared__ alignas(16) short smA [128 * 64];
  __shared__ alignas(16) short smBh[128 * 64];
  __shared__ alignas(16) short smBl[128 * 64];

  const int tid  = threadIdx.x;
  const int lane = tid & 63;
  const int quad = lane >> 4;
  const int l15  = lane & 15;
  const int wv   = tid >> 6;
  const int wm   = wv & 1;
  const int wn   = wv >> 1;

  const size_t r0 = (size_t)blockIdx.x * 128;
  const int    d0 = blockIdx.y * 128;

  int srow[4], sg8[4];
#pragma unroll
  for (int j = 0; j < 4; ++j) {
    int gi  = j * 256 + tid;
    srow[j] = gi >> 3;
    sg8[j]  = ((gi & 7) ^ (srow[j] & 7)) * 8;
  }

  const unsigned short* ab  = spikes + r0 * 2048;
  const unsigned short* bhb = w2h + (size_t)d0 * 2048;
  const unsigned short* blb = w2l + (size_t)d0 * 2048;

  f32x4 acc[4][4] = {};

  for (int k0 = 0; k0 < 2048; k0 += 64) {
    __syncthreads();
#pragma unroll
    for (int j = 0; j < 4; ++j) {
      load_lds16(ab  + (size_t)srow[j] * 2048 + k0 + sg8[j],
                 &smA [(j * 256 + tid) * 8]);
      load_lds16(bhb + (size_t)srow[j] * 2048 + k0 + sg8[j],
                 &smBh[(j * 256 + tid) * 8]);
      load_lds16(blb + (size_t)srow[j] * 2048 + k0 + sg8[j],
                 &smBl[(j * 256 + tid) * 8]);
    }
    __syncthreads();

#pragma unroll
    for (int ks = 0; ks < 2; ++ks) {
      short8 af[4], bh[4], bl[4];
#pragma unroll
      for (int mi = 0; mi < 4; ++mi) {
        int m = wm * 64 + mi * 16 + l15;
        af[mi] = ((const short8*)smA)[m * 8 + ((ks * 4 + quad) ^ (m & 7))];
      }
#pragma unroll
      for (int ni = 0; ni < 4; ++ni) {
        int n = wn * 64 + ni * 16 + l15;
        int sl = n * 8 + ((ks * 4 + quad) ^ (n & 7));
        bh[ni] = ((const short8*)smBh)[sl];
        bl[ni] = ((const short8*)smBl)[sl];
      }
#pragma unroll
      for (int mi = 0; mi < 4; ++mi)
#pragma unroll
        for (int ni = 0; ni < 4; ++ni) {
          acc[mi][ni] = __builtin_amdgcn_mfma_f32_16x16x32_bf16(
              af[mi], bh[ni], acc[mi][ni], 0, 0, 0);
          acc[mi][ni] = __builtin_amdgcn_mfma_f32_16x16x32_bf16(
              af[mi], bl[ni], acc[mi][ni], 0, 0, 0);
        }
    }
  }

  float* ob = out + r0 * 512 + d0;
#pragma unroll
  for (int mi = 0; mi < 4; ++mi)
#pragma unroll
    for (int ni = 0; ni < 4; ++ni)
#pragma unroll
      for (int r = 0; r < 4; ++r) {
        int rr = wm * 64 + mi * 16 + quad * 4 + r;
        int cc = wn * 64 + ni * 16 + l15;
        ob[(size_t)rr * 512 + cc] = acc[mi][ni][r];
      }
}

// ---------------------------------------------------------------------------
// K2 fallback (no extra ws): out = spikes @ w2^T, fp32 VALU. Grid (256, 8).
// ---------------------------------------------------------------------------
#define KT 16
#define PADF 68

__global__ __launch_bounds__(256) void k2_gemm_valu(
    const unsigned short* __restrict__ spikes,
    const float* __restrict__ w2,
    float* __restrict__ out)
{
  __shared__ float sA[KT][PADF];
  __shared__ float sB[KT][PADF];

  const int tid = threadIdx.x;
  const int tx  = tid & 15;
  const int ty  = tid >> 4;
  const int lr  = tid >> 2;
  const int lg  = tid & 3;

  const size_t r0 = (size_t)blockIdx.x * 64;
  const int    d0 = blockIdx.y * 64;

  float acc[4][4];
#pragma unroll
  for (int i = 0; i < 4; ++i)
#pragma unroll
    for (int j = 0; j < 4; ++j) acc[i][j] = 0.0f;

  for (int k0 = 0; k0 < 2048; k0 += KT) {
    __syncthreads();
    ushort4 av = *(const ushort4*)&spikes[(r0 + lr) * 2048 + k0 + lg * 4];
    float4  bv = *(const float4*)&w2[(size_t)(d0 + lr) * 2048 + k0 + lg * 4];
    sA[lg * 4 + 0][lr] = bf2f(av.x); sA[lg * 4 + 1][lr] = bf2f(av.y);
    sA[lg * 4 + 2][lr] = bf2f(av.z); sA[lg * 4 + 3][lr] = bf2f(av.w);
    sB[lg * 4 + 0][lr] = bv.x; sB[lg * 4 + 1][lr] = bv.y;
    sB[lg * 4 + 2][lr] = bv.z; sB[lg * 4 + 3][lr] = bv.w;
    __syncthreads();

#pragma unroll
    for (int k = 0; k < KT; ++k) {
      float4 a4 = *(const float4*)&sA[k][ty * 4];
      float4 b4 = *(const float4*)&sB[k][tx * 4];
      float aa[4] = {a4.x, a4.y, a4.z, a4.w};
      float bb[4] = {b4.x, b4.y, b4.z, b4.w};
#pragma unroll
      for (int i = 0; i < 4; ++i)
#pragma unroll
        for (int j = 0; j < 4; ++j)
          acc[i][j] = __builtin_fmaf(aa[i], bb[j], acc[i][j]);
    }
  }

#pragma unroll
  for (int i = 0; i < 4; ++i) {
    float4 o = make_float4(acc[i][0], acc[i][1], acc[i][2], acc[i][3]);
    *(float4*)&out[(r0 + ty * 4 + i) * 512 + d0 + tx * 4] = o;
  }
}

// ---------------------------------------------------------------------------
// K3: rate = count / 33554432 -> fp32 at d_out[8388608]
// ---------------------------------------------------------------------------
__global__ void k3_rate(const unsigned* __restrict__ cnt, float* __restrict__ dst) {
  dst[0] = (float)((double)(*cnt) / 33554432.0);
}

extern "C" void kernel_launch(void* const* d_in, const int* in_sizes, int n_in,
                              void* d_out, int out_size, void* d_ws, size_t ws_size,
                              hipStream_t stream) {
  const float* x  = (const float*)d_in[0];
  const float* w1 = (const float*)d_in[1];
  const float* w2 = (const float*)d_in[2];
  float* out = (float*)d_out;

  unsigned* cnt = (unsigned*)d_ws;
  unsigned short* spikes = (unsigned short*)((char*)d_ws + 256);
  const size_t SPIKES_B = (size_t)16384 * 2048 * 2;           // 67108864
  unsigned short* w2h = (unsigned short*)((char*)d_ws + 256 + SPIKES_B);
  unsigned short* w2l = w2h + (size_t)512 * 2048;
  const size_t NEED_SPLIT = 256 + SPIKES_B + 2 * (size_t)512 * 2048 * 2;
  float* xT  = (float*)((char*)d_ws + NEED_SPLIT);
  float* w1T = xT + (size_t)512 * 16384;
  const size_t NEED_FULL = NEED_SPLIT + ((size_t)512 * 16384 + 512 * 2048) * 4;

  hipMemsetAsync(d_ws, 0, 256, stream);  // zero the spike counter

  const bool has_split = ws_size >= NEED_SPLIT;
  const bool has_full  = ws_size >= NEED_FULL;

  if (has_full) {
    hipLaunchKernelGGL(k0x_xpose_x,  dim3(512), dim3(256), 0, stream, x, xT);
    hipLaunchKernelGGL(k0w_xpose_w1, dim3(256), dim3(256), 0, stream, w1, w1T);
    hipLaunchKernelGGL(k1_gemm_lif_dma, dim3(128, 16), dim3(256), 0, stream,
                       xT, w1T, spikes, cnt);
  } else {
    hipLaunchKernelGGL(k1_gemm_lif_legacy, dim3(128, 16), dim3(256), 0, stream,
                       x, w1, spikes, cnt);
  }

  if (has_split) {
    hipLaunchKernelGGL(k0_split, dim3(1024), dim3(256), 0, stream, w2, w2h, w2l);
    hipLaunchKernelGGL(k2_gemm_mfma, dim3(128, 4), dim3(256), 0, stream,
                       spikes, w2h, w2l, out);
  } else {
    hipLaunchKernelGGL(k2_gemm_valu, dim3(256, 8), dim3(256), 0, stream,
                       spikes, w2, out);
  }

  hipLaunchKernelGGL(k3_rate, dim3(1), dim3(1), 0, stream, cnt, out + 8388608);
}

// Round 7
// 4643.980 us; speedup vs baseline: 1.2382x; 1.2382x over previous
//
#include <hip/hip_runtime.h>
#include <stdint.h>

// ---------------------------------------------------------------------------
// SpikeMLP (all fp32 I/O):
//   h = x @ w1^T            (16384,512)x(2048,512)^T -> (16384,2048)
//   spikes,rate = LIF(h)    scan over t (4 steps, rows grouped (b,t,s))
//   out = spikes @ w2^T     (16384,2048)x(512,2048)^T -> (16384,512)
//
// Numerics contract (DO NOT BREAK):
//   - GEMM1 (k1): per-element f32 sequential FMA over k=0..511 ascending,
//     one accumulator -> bit-exact match of the np reference's h.
//   - LIF: vv = __fmul_rn(0.95f, v); vv = __fadd_rn(vv, h); spike = vv > 1.
//   - GEMM2 is continuous in spikes {0,1} -> MFMA allowed (w2 hi+lo bf16).
//
// k1 (round 14): round-6 DMA kernel with launch_bounds(256,4).
//   ROUND-6 POST-MORTEM: DMA schedule passed bit-exact (indexing verified)
//   but __launch_bounds__(256,5) capped the allocator at ~102 VGPR; the
//   64-reg acc + 16-deep unrolled compute missed the budget -> full spill
//   cascade (VGPR 48, VALUBusy 4.7%, 18 GB scratch/dispatch, 5.6 ms).
//   Single-variable fix: bounds (256,4) = 128 VGPR budget, proven to hold
//   this compute body at VGPR 56-64 across rounds 1/4/5. Everything else
//   unchanged from round 6:
//   - One-time prep: xT[k][b][s][t] (33.5 MB), w1T[k][h] (4 MB): each k-row
//     of a block's A/B tile = 128 contiguous floats -> global_load_lds
//     stages straight into [k][128] LDS (zero staging VALU / VGPR).
//   - K-chunk 16, 2 buffer pairs (32 KB LDS), 8x8 micro.
//   - Loop: issue(c+1) -> s_waitcnt vmcnt(4) -> s_barrier -> compute(c)
//     -> lgkmcnt(0)+s_barrier. vmcnt NEVER drains to 0 in the main loop.
//   - A-reads 16-lane broadcast (64 B/instr), B-reads 2-sweep (free).
//   Spill tripwire for the post-mortem: WRITE_SIZE must be ~65792 KB
//   (spikes only). Legacy round-1 k1 kept as ws fallback.
// ---------------------------------------------------------------------------

typedef __attribute__((ext_vector_type(8))) short short8;   // 8 bf16 = 16 B
typedef __attribute__((ext_vector_type(4))) float f32x4;

#define AS1 __attribute__((address_space(1)))
#define AS3 __attribute__((address_space(3)))

__device__ __forceinline__ void load_lds16(const void* g, void* l) {
  __builtin_amdgcn_global_load_lds((const AS1 void*)g, (AS3 void*)l, 16, 0, 0);
}

__device__ __forceinline__ unsigned short f2bf(float f) {
  union { float f; unsigned u; } un; un.f = f;
  unsigned r = un.u + 0x7FFF + ((un.u >> 16) & 1);   // RNE
  return (unsigned short)(r >> 16);
}
__device__ __forceinline__ float bf2f(unsigned short u) {
  union { unsigned u; float f; } un; un.u = ((unsigned)u) << 16; return un.f;
}

// ---------------------------------------------------------------------------
// K0: split w2 (fp32) into bf16 hi + lo.
// ---------------------------------------------------------------------------
__global__ __launch_bounds__(256) void k0_split(
    const float* __restrict__ w2, unsigned short* __restrict__ hi,
    unsigned short* __restrict__ lo)
{
  int i = (blockIdx.x * 256 + threadIdx.x) * 4;
  float4 w = *(const float4*)&w2[i];
  unsigned short h4[4], l4[4];
  float ws[4] = {w.x, w.y, w.z, w.w};
#pragma unroll
  for (int c = 0; c < 4; ++c) {
    unsigned short h = f2bf(ws[c]);
    h4[c] = h;
    l4[c] = f2bf(ws[c] - bf2f(h));
  }
  *(ushort4*)&hi[i] = *(const ushort4*)h4;
  *(ushort4*)&lo[i] = *(const ushort4*)l4;
}

// ---------------------------------------------------------------------------
// K0X: xT[((k*16+b)*256+s)*4 + t] = x[((b*4+t)*256+s)*512 + k]
// Per k, a k1-block's 128 A-rows (p = sl*4+t) become 128 contiguous floats.
// Grid 512 blocks: bx -> b = bx>>5, st = (bx>>3)&3, kt = bx&7. 256 thr.
// ---------------------------------------------------------------------------
__global__ __launch_bounds__(256) void k0x_xpose_x(
    const float* __restrict__ x, float* __restrict__ xT)
{
  __shared__ float tile4[64 * 256];   // [kl][sl*4+t], 64 KB

  const int tid = threadIdx.x;
  const int b  = blockIdx.x >> 5;
  const int st = (blockIdx.x >> 3) & 3;
  const int kt = blockIdx.x & 7;
  const int s0 = st * 64;
  const int k0 = kt * 64;

  const int sl = tid >> 2;            // 0..63
#pragma unroll
  for (int t = 0; t < 4; ++t) {
    const float* xrow = x + ((size_t)((b * 4 + t) * 256) + s0 + sl) * 512 + k0;
#pragma unroll
    for (int u = 0; u < 4; ++u) {
      const int klb = (tid & 3) * 4 + u * 16;
      float4 v = *(const float4*)&xrow[klb];
      tile4[(klb + 0) * 256 + sl * 4 + t] = v.x;
      tile4[(klb + 1) * 256 + sl * 4 + t] = v.y;
      tile4[(klb + 2) * 256 + sl * 4 + t] = v.z;
      tile4[(klb + 3) * 256 + sl * 4 + t] = v.w;
    }
  }
  __syncthreads();

#pragma unroll
  for (int w = 0; w < 16; ++w) {
    const int kl = w * 4 + (tid >> 6);
    const size_t g = (size_t)((k0 + kl) * 16 + b) * 1024 + s0 * 4 + (tid & 63) * 4;
    *(float4*)&xT[g] = *(const float4*)&tile4[kl * 256 + (tid & 63) * 4];
  }
}

// ---------------------------------------------------------------------------
// K0W: w1T[k][h] = w1[h][k].  Grid 256 blocks: ht = bx>>3, kt = bx&7.
// ---------------------------------------------------------------------------
__global__ __launch_bounds__(256) void k0w_xpose_w1(
    const float* __restrict__ w1, float* __restrict__ w1T)
{
  __shared__ float tile[64 * 68];

  const int tid = threadIdx.x;
  const int h0 = (blockIdx.x >> 3) * 64;
  const int k0 = (blockIdx.x & 7) * 64;

  const int hl = tid >> 2;
#pragma unroll
  for (int u = 0; u < 4; ++u) {
    const int klb = (tid & 3) * 4 + u * 16;
    float4 v = *(const float4*)&w1[(size_t)(h0 + hl) * 512 + k0 + klb];
    tile[(klb + 0) * 68 + hl] = v.x;
    tile[(klb + 1) * 68 + hl] = v.y;
    tile[(klb + 2) * 68 + hl] = v.z;
    tile[(klb + 3) * 68 + hl] = v.w;
  }
  __syncthreads();

#pragma unroll
  for (int it = 0; it < 16; ++it) {
    const int kl = it * 4 + (tid >> 6);
    w1T[(size_t)(k0 + kl) * 2048 + h0 + (tid & 63)] = tile[kl * 68 + (tid & 63)];
  }
}

// ---------------------------------------------------------------------------
// K1 (DMA): fused GEMM1 + thread-local LIF.  Tile 128x128 (p = sl*4+t),
// 256 thr, 8x8 micro.  Grid (128,16).
// ---------------------------------------------------------------------------
#define K1_COMPUTE(SA, SB)                                                 \
  do {                                                                     \
    _Pragma("unroll")                                                      \
    for (int k = 0; k < 16; ++k) {                                         \
      float4 va0 = *(const float4*)&SA[ty * 8 + k * 128];                  \
      float4 va1 = *(const float4*)&SA[ty * 8 + 4 + k * 128];              \
      float4 vb0 = *(const float4*)&SB[tx * 4 + k * 128];                  \
      float4 vb1 = *(const float4*)&SB[tx * 4 + 64 + k * 128];             \
      float av[8] = {va0.x, va0.y, va0.z, va0.w,                           \
                     va1.x, va1.y, va1.z, va1.w};                          \
      float bv[8] = {vb0.x, vb0.y, vb0.z, vb0.w,                           \
                     vb1.x, vb1.y, vb1.z, vb1.w};                          \
      _Pragma("unroll")                                                    \
      for (int m = 0; m < 8; ++m)                                          \
        _Pragma("unroll")                                                  \
        for (int j = 0; j < 8; ++j)                                        \
          acc[m][j] = __builtin_fmaf(av[m], bv[j], acc[m][j]);             \
    }                                                                      \
  } while (0)

// issue one 16-k chunk: 4 global_load_lds (A lo/hi k-half, B lo/hi).
#define K1_ISSUE(CHUNK, DA, DB)                                            \
  do {                                                                     \
    const float* _sA = xT + (size_t)((CHUNK) * 16 + kk) * 16384 + aOff;    \
    const float* _sB = w1T + (size_t)((CHUNK) * 16 + kk) * 2048 + bOff;    \
    load_lds16(_sA,              (DA) + wuB);                              \
    load_lds16(_sA + 8 * 16384,  (DA) + wuB + 1024);                       \
    load_lds16(_sB,              (DB) + wuB);                              \
    load_lds16(_sB + 8 * 2048,   (DB) + wuB + 1024);                       \
  } while (0)

#define K1_W4B() asm volatile("s_waitcnt vmcnt(4)\ns_barrier" ::: "memory")
#define K1_W0B() asm volatile("s_waitcnt vmcnt(0)\ns_barrier" ::: "memory")
#define K1_LGB() asm volatile("s_waitcnt lgkmcnt(0)\ns_barrier" ::: "memory")

__global__ __launch_bounds__(256, 4) void k1_gemm_lif_dma(
    const float* __restrict__ xT,         // (512,16,256,4) transposed x
    const float* __restrict__ w1T,        // (512, 2048) transposed w1
    unsigned short* __restrict__ spikes,  // (16384, 2048) bf16 {0,1}
    unsigned* __restrict__ cnt_out)
{
  __shared__ float sA0[16 * 128];   // 8 KB each, 32 KB total
  __shared__ float sB0[16 * 128];
  __shared__ float sA1[16 * 128];
  __shared__ float sB1[16 * 128];

  const int tid = threadIdx.x;
  const int tx  = tid & 15;    // col group: cols tx*4..+3 and 64+tx*4..+3
  const int ty  = tid >> 4;    // s-pair index: sl = ty*2 + i

  const int bx = blockIdx.x;
  const int b  = bx >> 3;
  const int s0 = (bx & 7) * 32;
  const int h0 = blockIdx.y * 128;

  // DMA addressing: lane loads 16 B of k-row kk at p-quad (tid&31)*4.
  const int kk   = tid >> 5;                        // 0..7
  const int aOff = (b * 256 + s0) * 4 + (tid & 31) * 4;
  const int bOff = h0 + (tid & 31) * 4;
  const int wuB  = (tid >> 6) * 256;                // wave-uniform LDS base (floats)

  float acc[8][8];
#pragma unroll
  for (int m = 0; m < 8; ++m)
#pragma unroll
    for (int j = 0; j < 8; ++j) acc[m][j] = 0.0f;

  K1_ISSUE(0, sA0, sB0);

  for (int c = 0; c < 32; c += 2) {
    // ---- chunk c in buf0 ----
    K1_ISSUE(c + 1, sA1, sB1);
    K1_W4B();                       // chunk-c DMA done (4 newest stay in flight)
    K1_COMPUTE(sA0, sB0);
    K1_LGB();                       // close reads of buf0 before its next DMA
    // ---- chunk c+1 in buf1 ----
    if (c < 30) { K1_ISSUE(c + 2, sA0, sB0); K1_W4B(); }
    else        { K1_W0B(); }
    K1_COMPUTE(sA1, sB1);
    if (c < 30) K1_LGB();
  }

  // Epilogue: LIF. Thread owns all 4 t of its 2 s-rows -> local chain.
  unsigned cnt = 0;
#pragma unroll
  for (int i = 0; i < 2; ++i) {
    unsigned short sp[4][8];
#pragma unroll
    for (int j = 0; j < 8; ++j) {
      float v = 0.0f;
#pragma unroll
      for (int t = 0; t < 4; ++t) {
        float vv = __fadd_rn(__fmul_rn(0.95f, v), acc[i * 4 + t][j]);
        bool s = vv > 1.0f;                 // numpy op-for-op
        sp[t][j] = s ? (unsigned short)0x3F80 : (unsigned short)0;
        cnt += s ? 1u : 0u;
        v = s ? 0.0f : vv;
      }
    }
#pragma unroll
    for (int t = 0; t < 4; ++t) {
      size_t grow = ((size_t)(b * 4 + t) << 8) + s0 + ty * 2 + i;
      unsigned short* rowp = spikes + grow * 2048 + h0;
      ushort4 o0, o1;
      o0.x = sp[t][0]; o0.y = sp[t][1]; o0.z = sp[t][2]; o0.w = sp[t][3];
      o1.x = sp[t][4]; o1.y = sp[t][5]; o1.z = sp[t][6]; o1.w = sp[t][7];
      *(ushort4*)&rowp[tx * 4]      = o0;
      *(ushort4*)&rowp[64 + tx * 4] = o1;
    }
  }

#pragma unroll
  for (int off = 32; off; off >>= 1) cnt += __shfl_down(cnt, off);
  if ((tid & 63) == 0) atomicAdd(cnt_out, cnt);
}

// ---------------------------------------------------------------------------
// K1 legacy (round-1, 390 us): used when ws lacks room for xT/w1T.
// ---------------------------------------------------------------------------
#define L_KT 16
#define L_SA 176
#define L_SB 176

__global__ __launch_bounds__(256, 4) void k1_gemm_lif_legacy(
    const float* __restrict__ x,
    const float* __restrict__ w1,
    unsigned short* __restrict__ spikes,
    unsigned* __restrict__ cnt_out)
{
  __shared__ float sA[L_KT * L_SA];
  __shared__ float sB[L_KT * L_SB];

  const int tid = threadIdx.x;
  const int tx  = tid & 15;
  const int ty  = tid >> 4;

  const int bx = blockIdx.x;
  const int b  = bx >> 3;
  const int s0 = (bx & 7) * 32;
  const int h0 = blockIdx.y * 128;

  const int kg = tid & 3;
  const int u  = tid >> 2;

  float acc[8][8];
#pragma unroll
  for (int m = 0; m < 8; ++m)
#pragma unroll
    for (int j = 0; j < 8; ++j) acc[m][j] = 0.0f;

  const size_t growA0 = ((size_t)(b * 4 + (u & 3)) << 8) + s0 + (u >> 2);
  const size_t growA1 = growA0 + 16;
  const float* xA0 = x  + growA0 * 512 + kg * 4;
  const float* xA1 = x  + growA1 * 512 + kg * 4;
  const float* wB0 = w1 + (size_t)(h0 + u) * 512 + kg * 4;
  const float* wB1 = w1 + (size_t)(h0 + u + 64) * 512 + kg * 4;

  float* sAw = &sA[(4 * kg) * L_SA + u + 16 * kg];
  float* sBw = &sB[(4 * kg) * L_SB + u + 16 * kg];

  const float* sAr = &sA[ty * 8];
  const float* sBr = &sB[tx * 4];

  for (int k0 = 0; k0 < 512; k0 += L_KT) {
    float4 a0v = *(const float4*)(xA0 + k0);
    float4 a1v = *(const float4*)(xA1 + k0);
    float4 b0v = *(const float4*)(wB0 + k0);
    float4 b1v = *(const float4*)(wB1 + k0);

    __syncthreads();
    {
      float a0s[4] = {a0v.x, a0v.y, a0v.z, a0v.w};
      float a1s[4] = {a1v.x, a1v.y, a1v.z, a1v.w};
      float b0s[4] = {b0v.x, b0v.y, b0v.z, b0v.w};
      float b1s[4] = {b1v.x, b1v.y, b1v.z, b1v.w};
#pragma unroll
      for (int c = 0; c < 4; ++c) {
        sAw[c * L_SA]      = a0s[c];
        sAw[c * L_SA + 64] = a1s[c];
        sBw[c * L_SB]      = b0s[c];
        sBw[c * L_SB + 64] = b1s[c];
      }
    }
    __syncthreads();

#pragma unroll
    for (int k = 0; k < L_KT; ++k) {
      const int off = k * L_SA + 16 * (k >> 2);
      float4 va0 = *(const float4*)(sAr + off);
      float4 va1 = *(const float4*)(sAr + off + 4);
      float4 vb0 = *(const float4*)(sBr + off);
      float4 vb1 = *(const float4*)(sBr + off + 64);
      float av[8] = {va0.x, va0.y, va0.z, va0.w, va1.x, va1.y, va1.z, va1.w};
      float bv[8] = {vb0.x, vb0.y, vb0.z, vb0.w, vb1.x, vb1.y, vb1.z, vb1.w};
#pragma unroll
      for (int m = 0; m < 8; ++m)
#pragma unroll
        for (int j = 0; j < 8; ++j)
          acc[m][j] = __builtin_fmaf(av[m], bv[j], acc[m][j]);
    }
  }

  unsigned cnt = 0;
#pragma unroll
  for (int i = 0; i < 2; ++i) {
    unsigned short sp[4][8];
#pragma unroll
    for (int j = 0; j < 8; ++j) {
      float v = 0.0f;
#pragma unroll
      for (int t = 0; t < 4; ++t) {
        float vv = __fadd_rn(__fmul_rn(0.95f, v), acc[i * 4 + t][j]);
        bool s = vv > 1.0f;
        sp[t][j] = s ? (unsigned short)0x3F80 : (unsigned short)0;
        cnt += s ? 1u : 0u;
        v = s ? 0.0f : vv;
      }
    }
#pragma unroll
    for (int t = 0; t < 4; ++t) {
      size_t grow = ((size_t)(b * 4 + t) << 8) + s0 + ty * 2 + i;
      unsigned short* rowp = spikes + grow * 2048 + h0;
      ushort4 o0, o1;
      o0.x = sp[t][0]; o0.y = sp[t][1]; o0.z = sp[t][2]; o0.w = sp[t][3];
      o1.x = sp[t][4]; o1.y = sp[t][5]; o1.z = sp[t][6]; o1.w = sp[t][7];
      *(ushort4*)&rowp[tx * 4]      = o0;
      *(ushort4*)&rowp[64 + tx * 4] = o1;
    }
  }

#pragma unroll
  for (int off = 32; off; off >>= 1) cnt += __shfl_down(cnt, off);
  if ((tid & 63) == 0) atomicAdd(cnt_out, cnt);
}

// ---------------------------------------------------------------------------
// K2: out = spikes @ (w2_hi + w2_lo)^T via bf16 MFMA, fp32 accum.
// ---------------------------------------------------------------------------
__global__ __launch_bounds__(256, 2) void k2_gemm_mfma(
    const unsigned short* __restrict__ spikes,
    const unsigned short* __restrict__ w2h,
    const unsigned short* __restrict__ w2l,
    float* __restrict__ out)
{
  __shared__ alignas(16) short smA [128 * 64];
  __shared__ alignas(16) short smBh[128 * 64];
  __shared__ alignas(16) short smBl[128 * 64];

  const int tid  = threadIdx.x;
  const int lane = tid & 63;
  const int quad = lane >> 4;
  const int l15  = lane & 15;
  const int wv   = tid >> 6;
  const int wm   = wv & 1;
  const int wn   = wv >> 1;

  const size_t r0 = (size_t)blockIdx.x * 128;
  const int    d0 = blockIdx.y * 128;

  int srow[4], sg8[4];
#pragma unroll
  for (int j = 0; j < 4; ++j) {
    int gi  = j * 256 + tid;
    srow[j] = gi >> 3;
    sg8[j]  = ((gi & 7) ^ (srow[j] & 7)) * 8;
  }

  const unsigned short* ab  = spikes + r0 * 2048;
  const unsigned short* bhb = w2h + (size_t)d0 * 2048;
  const unsigned short* blb = w2l + (size_t)d0 * 2048;

  f32x4 acc[4][4] = {};

  for (int k0 = 0; k0 < 2048; k0 += 64) {
    __syncthreads();
#pragma unroll
    for (int j = 0; j < 4; ++j) {
      load_lds16(ab  + (size_t)srow[j] * 2048 + k0 + sg8[j],
                 &smA [(j * 256 + tid) * 8]);
      load_lds16(bhb + (size_t)srow[j] * 2048 + k0 + sg8[j],
                 &smBh[(j * 256 + tid) * 8]);
      load_lds16(blb + (size_t)srow[j] * 2048 + k0 + sg8[j],
                 &smBl[(j * 256 + tid) * 8]);
    }
    __syncthreads();

#pragma unroll
    for (int ks = 0; ks < 2; ++ks) {
      short8 af[4], bh[4], bl[4];
#pragma unroll
      for (int mi = 0; mi < 4; ++mi) {
        int m = wm * 64 + mi * 16 + l15;
        af[mi] = ((const short8*)smA)[m * 8 + ((ks * 4 + quad) ^ (m & 7))];
      }
#pragma unroll
      for (int ni = 0; ni < 4; ++ni) {
        int n = wn * 64 + ni * 16 + l15;
        int sl = n * 8 + ((ks * 4 + quad) ^ (n & 7));
        bh[ni] = ((const short8*)smBh)[sl];
        bl[ni] = ((const short8*)smBl)[sl];
      }
#pragma unroll
      for (int mi = 0; mi < 4; ++mi)
#pragma unroll
        for (int ni = 0; ni < 4; ++ni) {
          acc[mi][ni] = __builtin_amdgcn_mfma_f32_16x16x32_bf16(
              af[mi], bh[ni], acc[mi][ni], 0, 0, 0);
          acc[mi][ni] = __builtin_amdgcn_mfma_f32_16x16x32_bf16(
              af[mi], bl[ni], acc[mi][ni], 0, 0, 0);
        }
    }
  }

  float* ob = out + r0 * 512 + d0;
#pragma unroll
  for (int mi = 0; mi < 4; ++mi)
#pragma unroll
    for (int ni = 0; ni < 4; ++ni)
#pragma unroll
      for (int r = 0; r < 4; ++r) {
        int rr = wm * 64 + mi * 16 + quad * 4 + r;
        int cc = wn * 64 + ni * 16 + l15;
        ob[(size_t)rr * 512 + cc] = acc[mi][ni][r];
      }
}

// ---------------------------------------------------------------------------
// K2 fallback (no extra ws): out = spikes @ w2^T, fp32 VALU. Grid (256, 8).
// ---------------------------------------------------------------------------
#define KT 16
#define PADF 68

__global__ __launch_bounds__(256) void k2_gemm_valu(
    const unsigned short* __restrict__ spikes,
    const float* __restrict__ w2,
    float* __restrict__ out)
{
  __shared__ float sA[KT][PADF];
  __shared__ float sB[KT][PADF];

  const int tid = threadIdx.x;
  const int tx  = tid & 15;
  const int ty  = tid >> 4;
  const int lr  = tid >> 2;
  const int lg  = tid & 3;

  const size_t r0 = (size_t)blockIdx.x * 64;
  const int    d0 = blockIdx.y * 64;

  float acc[4][4];
#pragma unroll
  for (int i = 0; i < 4; ++i)
#pragma unroll
    for (int j = 0; j < 4; ++j) acc[i][j] = 0.0f;

  for (int k0 = 0; k0 < 2048; k0 += KT) {
    __syncthreads();
    ushort4 av = *(const ushort4*)&spikes[(r0 + lr) * 2048 + k0 + lg * 4];
    float4  bv = *(const float4*)&w2[(size_t)(d0 + lr) * 2048 + k0 + lg * 4];
    sA[lg * 4 + 0][lr] = bf2f(av.x); sA[lg * 4 + 1][lr] = bf2f(av.y);
    sA[lg * 4 + 2][lr] = bf2f(av.z); sA[lg * 4 + 3][lr] = bf2f(av.w);
    sB[lg * 4 + 0][lr] = bv.x; sB[lg * 4 + 1][lr] = bv.y;
    sB[lg * 4 + 2][lr] = bv.z; sB[lg * 4 + 3][lr] = bv.w;
    __syncthreads();

#pragma unroll
    for (int k = 0; k < KT; ++k) {
      float4 a4 = *(const float4*)&sA[k][ty * 4];
      float4 b4 = *(const float4*)&sB[k][tx * 4];
      float aa[4] = {a4.x, a4.y, a4.z, a4.w};
      float bb[4] = {b4.x, b4.y, b4.z, b4.w};
#pragma unroll
      for (int i = 0; i < 4; ++i)
#pragma unroll
        for (int j = 0; j < 4; ++j)
          acc[i][j] = __builtin_fmaf(aa[i], bb[j], acc[i][j]);
    }
  }

#pragma unroll
  for (int i = 0; i < 4; ++i) {
    float4 o = make_float4(acc[i][0], acc[i][1], acc[i][2], acc[i][3]);
    *(float4*)&out[(r0 + ty * 4 + i) * 512 + d0 + tx * 4] = o;
  }
}

// ---------------------------------------------------------------------------
// K3: rate = count / 33554432 -> fp32 at d_out[8388608]
// ---------------------------------------------------------------------------
__global__ void k3_rate(const unsigned* __restrict__ cnt, float* __restrict__ dst) {
  dst[0] = (float)((double)(*cnt) / 33554432.0);
}

extern "C" void kernel_launch(void* const* d_in, const int* in_sizes, int n_in,
                              void* d_out, int out_size, void* d_ws, size_t ws_size,
                              hipStream_t stream) {
  const float* x  = (const float*)d_in[0];
  const float* w1 = (const float*)d_in[1];
  const float* w2 = (const float*)d_in[2];
  float* out = (float*)d_out;

  unsigned* cnt = (unsigned*)d_ws;
  unsigned short* spikes = (unsigned short*)((char*)d_ws + 256);
  const size_t SPIKES_B = (size_t)16384 * 2048 * 2;           // 67108864
  unsigned short* w2h = (unsigned short*)((char*)d_ws + 256 + SPIKES_B);
  unsigned short* w2l = w2h + (size_t)512 * 2048;
  const size_t NEED_SPLIT = 256 + SPIKES_B + 2 * (size_t)512 * 2048 * 2;
  float* xT  = (float*)((char*)d_ws + NEED_SPLIT);
  float* w1T = xT + (size_t)512 * 16384;
  const size_t NEED_FULL = NEED_SPLIT + ((size_t)512 * 16384 + 512 * 2048) * 4;

  hipMemsetAsync(d_ws, 0, 256, stream);  // zero the spike counter

  const bool has_split = ws_size >= NEED_SPLIT;
  const bool has_full  = ws_size >= NEED_FULL;

  if (has_full) {
    hipLaunchKernelGGL(k0x_xpose_x,  dim3(512), dim3(256), 0, stream, x, xT);
    hipLaunchKernelGGL(k0w_xpose_w1, dim3(256), dim3(256), 0, stream, w1, w1T);
    hipLaunchKernelGGL(k1_gemm_lif_dma, dim3(128, 16), dim3(256), 0, stream,
                       xT, w1T, spikes, cnt);
  } else {
    hipLaunchKernelGGL(k1_gemm_lif_legacy, dim3(128, 16), dim3(256), 0, stream,
                       x, w1, spikes, cnt);
  }

  if (has_split) {
    hipLaunchKernelGGL(k0_split, dim3(1024), dim3(256), 0, stream, w2, w2h, w2l);
    hipLaunchKernelGGL(k2_gemm_mfma, dim3(128, 4), dim3(256), 0, stream,
                       spikes, w2h, w2l, out);
  } else {
    hipLaunchKernelGGL(k2_gemm_valu, dim3(256, 8), dim3(256), 0, stream,
                       spikes, w2, out);
  }

  hipLaunchKernelGGL(k3_rate, dim3(1), dim3(1), 0, stream, cnt, out + 8388608);
}

// Round 8
// 3508.410 us; speedup vs baseline: 1.6390x; 1.3237x over previous
//
#include <hip/hip_runtime.h>
#include <stdint.h>

// ---------------------------------------------------------------------------
// SpikeMLP (all fp32 I/O):
//   h = x @ w1^T            (16384,512)x(2048,512)^T -> (16384,2048)
//   spikes,rate = LIF(h)    scan over t (4 steps, rows grouped (b,t,s))
//   out = spikes @ w2^T     (16384,2048)x(512,2048)^T -> (16384,512)
//
// Numerics contract (DO NOT BREAK):
//   - GEMM1 (k1): per-element f32 sequential FMA over k=0..511 ascending,
//     one accumulator -> bit-exact match of the np reference's h.
//   - LIF: vv = __fmul_rn(0.95f, v); vv = __fadd_rn(vv, h); spike = vv > 1.
//   - GEMM2 is continuous in spikes {0,1} -> MFMA allowed (w2 hi+lo bf16).
//
// k1 (round 15): round-6/7 DMA kernel with __launch_bounds__(256, 2).
//   EMPIRICAL ALLOCATOR LAW (this session): effective arch-VGPR budget is
//   ~256/N for __launch_bounds__(256,N):  N=2 -> 128 (r0, no spill at 128
//   live);  N=4 -> 56-64 (r1/r5/r7);  N=5 -> 48 (r6).  My r6/r7 sizing
//   assumed 512/N -> the DMA kernel's ~100-reg demand got a 64-reg budget
//   -> scratch cascade (WRITE 11.5 GB, VALUBusy 5%).  N=2 gives budget 128
//   >= demand (~105): no spill, occupancy then set by LDS/VGPR (4 blk/CU).
//   Everything else identical to the bit-exact-verified r6/r7 kernel:
//   - Prep: xT[k][b][s][t] (33.5 MB), w1T[k][h] (4 MB) -> each k-row of a
//     block tile is 128 contiguous floats -> global_load_lds stages direct
//     into [k][128] LDS (zero staging VALU / VGPR).
//   - K-chunk 16, 2 buffer pairs (32 KB LDS), 8x8 micro.
//   - Loop: issue(c+1) -> s_waitcnt vmcnt(4) -> s_barrier -> compute(c)
//     -> lgkmcnt(0)+s_barrier. vmcnt NEVER drains to 0 in the main loop.
//   Tripwire: WRITE_SIZE must be ~65792 KB (spikes only). If not, DMA lane
//   is dead -> revert to legacy k1, attack k2.
// ---------------------------------------------------------------------------

typedef __attribute__((ext_vector_type(8))) short short8;   // 8 bf16 = 16 B
typedef __attribute__((ext_vector_type(4))) float f32x4;

#define AS1 __attribute__((address_space(1)))
#define AS3 __attribute__((address_space(3)))

__device__ __forceinline__ void load_lds16(const void* g, void* l) {
  __builtin_amdgcn_global_load_lds((const AS1 void*)g, (AS3 void*)l, 16, 0, 0);
}

__device__ __forceinline__ unsigned short f2bf(float f) {
  union { float f; unsigned u; } un; un.f = f;
  unsigned r = un.u + 0x7FFF + ((un.u >> 16) & 1);   // RNE
  return (unsigned short)(r >> 16);
}
__device__ __forceinline__ float bf2f(unsigned short u) {
  union { unsigned u; float f; } un; un.u = ((unsigned)u) << 16; return un.f;
}

// ---------------------------------------------------------------------------
// K0: split w2 (fp32) into bf16 hi + lo.
// ---------------------------------------------------------------------------
__global__ __launch_bounds__(256) void k0_split(
    const float* __restrict__ w2, unsigned short* __restrict__ hi,
    unsigned short* __restrict__ lo)
{
  int i = (blockIdx.x * 256 + threadIdx.x) * 4;
  float4 w = *(const float4*)&w2[i];
  unsigned short h4[4], l4[4];
  float ws[4] = {w.x, w.y, w.z, w.w};
#pragma unroll
  for (int c = 0; c < 4; ++c) {
    unsigned short h = f2bf(ws[c]);
    h4[c] = h;
    l4[c] = f2bf(ws[c] - bf2f(h));
  }
  *(ushort4*)&hi[i] = *(const ushort4*)h4;
  *(ushort4*)&lo[i] = *(const ushort4*)l4;
}

// ---------------------------------------------------------------------------
// K0X: xT[((k*16+b)*256+s)*4 + t] = x[((b*4+t)*256+s)*512 + k]
// Per k, a k1-block's 128 A-rows (p = sl*4+t) become 128 contiguous floats.
// Grid 512 blocks: bx -> b = bx>>5, st = (bx>>3)&3, kt = bx&7. 256 thr.
// ---------------------------------------------------------------------------
__global__ __launch_bounds__(256) void k0x_xpose_x(
    const float* __restrict__ x, float* __restrict__ xT)
{
  __shared__ float tile4[64 * 256];   // [kl][sl*4+t], 64 KB

  const int tid = threadIdx.x;
  const int b  = blockIdx.x >> 5;
  const int st = (blockIdx.x >> 3) & 3;
  const int kt = blockIdx.x & 7;
  const int s0 = st * 64;
  const int k0 = kt * 64;

  const int sl = tid >> 2;            // 0..63
#pragma unroll
  for (int t = 0; t < 4; ++t) {
    const float* xrow = x + ((size_t)((b * 4 + t) * 256) + s0 + sl) * 512 + k0;
#pragma unroll
    for (int u = 0; u < 4; ++u) {
      const int klb = (tid & 3) * 4 + u * 16;
      float4 v = *(const float4*)&xrow[klb];
      tile4[(klb + 0) * 256 + sl * 4 + t] = v.x;
      tile4[(klb + 1) * 256 + sl * 4 + t] = v.y;
      tile4[(klb + 2) * 256 + sl * 4 + t] = v.z;
      tile4[(klb + 3) * 256 + sl * 4 + t] = v.w;
    }
  }
  __syncthreads();

#pragma unroll
  for (int w = 0; w < 16; ++w) {
    const int kl = w * 4 + (tid >> 6);
    const size_t g = (size_t)((k0 + kl) * 16 + b) * 1024 + s0 * 4 + (tid & 63) * 4;
    *(float4*)&xT[g] = *(const float4*)&tile4[kl * 256 + (tid & 63) * 4];
  }
}

// ---------------------------------------------------------------------------
// K0W: w1T[k][h] = w1[h][k].  Grid 256 blocks: ht = bx>>3, kt = bx&7.
// ---------------------------------------------------------------------------
__global__ __launch_bounds__(256) void k0w_xpose_w1(
    const float* __restrict__ w1, float* __restrict__ w1T)
{
  __shared__ float tile[64 * 68];

  const int tid = threadIdx.x;
  const int h0 = (blockIdx.x >> 3) * 64;
  const int k0 = (blockIdx.x & 7) * 64;

  const int hl = tid >> 2;
#pragma unroll
  for (int u = 0; u < 4; ++u) {
    const int klb = (tid & 3) * 4 + u * 16;
    float4 v = *(const float4*)&w1[(size_t)(h0 + hl) * 512 + k0 + klb];
    tile[(klb + 0) * 68 + hl] = v.x;
    tile[(klb + 1) * 68 + hl] = v.y;
    tile[(klb + 2) * 68 + hl] = v.z;
    tile[(klb + 3) * 68 + hl] = v.w;
  }
  __syncthreads();

#pragma unroll
  for (int it = 0; it < 16; ++it) {
    const int kl = it * 4 + (tid >> 6);
    w1T[(size_t)(k0 + kl) * 2048 + h0 + (tid & 63)] = tile[kl * 68 + (tid & 63)];
  }
}

// ---------------------------------------------------------------------------
// K1 (DMA): fused GEMM1 + thread-local LIF.  Tile 128x128 (p = sl*4+t),
// 256 thr, 8x8 micro.  Grid (128,16).
// ---------------------------------------------------------------------------
#define K1_COMPUTE(SA, SB)                                                 \
  do {                                                                     \
    _Pragma("unroll")                                                      \
    for (int k = 0; k < 16; ++k) {                                         \
      float4 va0 = *(const float4*)&SA[ty * 8 + k * 128];                  \
      float4 va1 = *(const float4*)&SA[ty * 8 + 4 + k * 128];              \
      float4 vb0 = *(const float4*)&SB[tx * 4 + k * 128];                  \
      float4 vb1 = *(const float4*)&SB[tx * 4 + 64 + k * 128];             \
      float av[8] = {va0.x, va0.y, va0.z, va0.w,                           \
                     va1.x, va1.y, va1.z, va1.w};                          \
      float bv[8] = {vb0.x, vb0.y, vb0.z, vb0.w,                           \
                     vb1.x, vb1.y, vb1.z, vb1.w};                          \
      _Pragma("unroll")                                                    \
      for (int m = 0; m < 8; ++m)                                          \
        _Pragma("unroll")                                                  \
        for (int j = 0; j < 8; ++j)                                        \
          acc[m][j] = __builtin_fmaf(av[m], bv[j], acc[m][j]);             \
    }                                                                      \
  } while (0)

// issue one 16-k chunk: 4 global_load_lds (A lo/hi k-half, B lo/hi).
#define K1_ISSUE(CHUNK, DA, DB)                                            \
  do {                                                                     \
    const float* _sA = xT + (size_t)((CHUNK) * 16 + kk) * 16384 + aOff;    \
    const float* _sB = w1T + (size_t)((CHUNK) * 16 + kk) * 2048 + bOff;    \
    load_lds16(_sA,              (DA) + wuB);                              \
    load_lds16(_sA + 8 * 16384,  (DA) + wuB + 1024);                       \
    load_lds16(_sB,              (DB) + wuB);                              \
    load_lds16(_sB + 8 * 2048,   (DB) + wuB + 1024);                       \
  } while (0)

#define K1_W4B() asm volatile("s_waitcnt vmcnt(4)\ns_barrier" ::: "memory")
#define K1_W0B() asm volatile("s_waitcnt vmcnt(0)\ns_barrier" ::: "memory")
#define K1_LGB() asm volatile("s_waitcnt lgkmcnt(0)\ns_barrier" ::: "memory")

__global__ __launch_bounds__(256, 2) void k1_gemm_lif_dma(
    const float* __restrict__ xT,         // (512,16,256,4) transposed x
    const float* __restrict__ w1T,        // (512, 2048) transposed w1
    unsigned short* __restrict__ spikes,  // (16384, 2048) bf16 {0,1}
    unsigned* __restrict__ cnt_out)
{
  __shared__ float sA0[16 * 128];   // 8 KB each, 32 KB total
  __shared__ float sB0[16 * 128];
  __shared__ float sA1[16 * 128];
  __shared__ float sB1[16 * 128];

  const int tid = threadIdx.x;
  const int tx  = tid & 15;    // col group: cols tx*4..+3 and 64+tx*4..+3
  const int ty  = tid >> 4;    // s-pair index: sl = ty*2 + i

  const int bx = blockIdx.x;
  const int b  = bx >> 3;
  const int s0 = (bx & 7) * 32;
  const int h0 = blockIdx.y * 128;

  // DMA addressing: lane loads 16 B of k-row kk at p-quad (tid&31)*4.
  const int kk   = tid >> 5;                        // 0..7
  const int aOff = (b * 256 + s0) * 4 + (tid & 31) * 4;
  const int bOff = h0 + (tid & 31) * 4;
  const int wuB  = (tid >> 6) * 256;                // wave-uniform LDS base (floats)

  float acc[8][8];
#pragma unroll
  for (int m = 0; m < 8; ++m)
#pragma unroll
    for (int j = 0; j < 8; ++j) acc[m][j] = 0.0f;

  K1_ISSUE(0, sA0, sB0);

  for (int c = 0; c < 32; c += 2) {
    // ---- chunk c in buf0 ----
    K1_ISSUE(c + 1, sA1, sB1);
    K1_W4B();                       // chunk-c DMA done (4 newest stay in flight)
    K1_COMPUTE(sA0, sB0);
    K1_LGB();                       // close reads of buf0 before its next DMA
    // ---- chunk c+1 in buf1 ----
    if (c < 30) { K1_ISSUE(c + 2, sA0, sB0); K1_W4B(); }
    else        { K1_W0B(); }
    K1_COMPUTE(sA1, sB1);
    if (c < 30) K1_LGB();
  }

  // Epilogue: LIF. Thread owns all 4 t of its 2 s-rows -> local chain.
  unsigned cnt = 0;
#pragma unroll
  for (int i = 0; i < 2; ++i) {
    unsigned short sp[4][8];
#pragma unroll
    for (int j = 0; j < 8; ++j) {
      float v = 0.0f;
#pragma unroll
      for (int t = 0; t < 4; ++t) {
        float vv = __fadd_rn(__fmul_rn(0.95f, v), acc[i * 4 + t][j]);
        bool s = vv > 1.0f;                 // numpy op-for-op
        sp[t][j] = s ? (unsigned short)0x3F80 : (unsigned short)0;
        cnt += s ? 1u : 0u;
        v = s ? 0.0f : vv;
      }
    }
#pragma unroll
    for (int t = 0; t < 4; ++t) {
      size_t grow = ((size_t)(b * 4 + t) << 8) + s0 + ty * 2 + i;
      unsigned short* rowp = spikes + grow * 2048 + h0;
      ushort4 o0, o1;
      o0.x = sp[t][0]; o0.y = sp[t][1]; o0.z = sp[t][2]; o0.w = sp[t][3];
      o1.x = sp[t][4]; o1.y = sp[t][5]; o1.z = sp[t][6]; o1.w = sp[t][7];
      *(ushort4*)&rowp[tx * 4]      = o0;
      *(ushort4*)&rowp[64 + tx * 4] = o1;
    }
  }

#pragma unroll
  for (int off = 32; off; off >>= 1) cnt += __shfl_down(cnt, off);
  if ((tid & 63) == 0) atomicAdd(cnt_out, cnt);
}

// ---------------------------------------------------------------------------
// K1 legacy (round-1, 390 us): used when ws lacks room for xT/w1T.
// ---------------------------------------------------------------------------
#define L_KT 16
#define L_SA 176
#define L_SB 176

__global__ __launch_bounds__(256, 4) void k1_gemm_lif_legacy(
    const float* __restrict__ x,
    const float* __restrict__ w1,
    unsigned short* __restrict__ spikes,
    unsigned* __restrict__ cnt_out)
{
  __shared__ float sA[L_KT * L_SA];
  __shared__ float sB[L_KT * L_SB];

  const int tid = threadIdx.x;
  const int tx  = tid & 15;
  const int ty  = tid >> 4;

  const int bx = blockIdx.x;
  const int b  = bx >> 3;
  const int s0 = (bx & 7) * 32;
  const int h0 = blockIdx.y * 128;

  const int kg = tid & 3;
  const int u  = tid >> 2;

  float acc[8][8];
#pragma unroll
  for (int m = 0; m < 8; ++m)
#pragma unroll
    for (int j = 0; j < 8; ++j) acc[m][j] = 0.0f;

  const size_t growA0 = ((size_t)(b * 4 + (u & 3)) << 8) + s0 + (u >> 2);
  const size_t growA1 = growA0 + 16;
  const float* xA0 = x  + growA0 * 512 + kg * 4;
  const float* xA1 = x  + growA1 * 512 + kg * 4;
  const float* wB0 = w1 + (size_t)(h0 + u) * 512 + kg * 4;
  const float* wB1 = w1 + (size_t)(h0 + u + 64) * 512 + kg * 4;

  float* sAw = &sA[(4 * kg) * L_SA + u + 16 * kg];
  float* sBw = &sB[(4 * kg) * L_SB + u + 16 * kg];

  const float* sAr = &sA[ty * 8];
  const float* sBr = &sB[tx * 4];

  for (int k0 = 0; k0 < 512; k0 += L_KT) {
    float4 a0v = *(const float4*)(xA0 + k0);
    float4 a1v = *(const float4*)(xA1 + k0);
    float4 b0v = *(const float4*)(wB0 + k0);
    float4 b1v = *(const float4*)(wB1 + k0);

    __syncthreads();
    {
      float a0s[4] = {a0v.x, a0v.y, a0v.z, a0v.w};
      float a1s[4] = {a1v.x, a1v.y, a1v.z, a1v.w};
      float b0s[4] = {b0v.x, b0v.y, b0v.z, b0v.w};
      float b1s[4] = {b1v.x, b1v.y, b1v.z, b1v.w};
#pragma unroll
      for (int c = 0; c < 4; ++c) {
        sAw[c * L_SA]      = a0s[c];
        sAw[c * L_SA + 64] = a1s[c];
        sBw[c * L_SB]      = b0s[c];
        sBw[c * L_SB + 64] = b1s[c];
      }
    }
    __syncthreads();

#pragma unroll
    for (int k = 0; k < L_KT; ++k) {
      const int off = k * L_SA + 16 * (k >> 2);
      float4 va0 = *(const float4*)(sAr + off);
      float4 va1 = *(const float4*)(sAr + off + 4);
      float4 vb0 = *(const float4*)(sBr + off);
      float4 vb1 = *(const float4*)(sBr + off + 64);
      float av[8] = {va0.x, va0.y, va0.z, va0.w, va1.x, va1.y, va1.z, va1.w};
      float bv[8] = {vb0.x, vb0.y, vb0.z, vb0.w, vb1.x, vb1.y, vb1.z, vb1.w};
#pragma unroll
      for (int m = 0; m < 8; ++m)
#pragma unroll
        for (int j = 0; j < 8; ++j)
          acc[m][j] = __builtin_fmaf(av[m], bv[j], acc[m][j]);
    }
  }

  unsigned cnt = 0;
#pragma unroll
  for (int i = 0; i < 2; ++i) {
    unsigned short sp[4][8];
#pragma unroll
    for (int j = 0; j < 8; ++j) {
      float v = 0.0f;
#pragma unroll
      for (int t = 0; t < 4; ++t) {
        float vv = __fadd_rn(__fmul_rn(0.95f, v), acc[i * 4 + t][j]);
        bool s = vv > 1.0f;
        sp[t][j] = s ? (unsigned short)0x3F80 : (unsigned short)0;
        cnt += s ? 1u : 0u;
        v = s ? 0.0f : vv;
      }
    }
#pragma unroll
    for (int t = 0; t < 4; ++t) {
      size_t grow = ((size_t)(b * 4 + t) << 8) + s0 + ty * 2 + i;
      unsigned short* rowp = spikes + grow * 2048 + h0;
      ushort4 o0, o1;
      o0.x = sp[t][0]; o0.y = sp[t][1]; o0.z = sp[t][2]; o0.w = sp[t][3];
      o1.x = sp[t][4]; o1.y = sp[t][5]; o1.z = sp[t][6]; o1.w = sp[t][7];
      *(ushort4*)&rowp[tx * 4]      = o0;
      *(ushort4*)&rowp[64 + tx * 4] = o1;
    }
  }

#pragma unroll
  for (int off = 32; off; off >>= 1) cnt += __shfl_down(cnt, off);
  if ((tid & 63) == 0) atomicAdd(cnt_out, cnt);
}

// ---------------------------------------------------------------------------
// K2: out = spikes @ (w2_hi + w2_lo)^T via bf16 MFMA, fp32 accum.
// ---------------------------------------------------------------------------
__global__ __launch_bounds__(256, 2) void k2_gemm_mfma(
    const unsigned short* __restrict__ spikes,
    const unsigned short* __restrict__ w2h,
    const unsigned short* __restrict__ w2l,
    float* __restrict__ out)
{
  __shared__ alignas(16) short smA [128 * 64];
  __shared__ alignas(16) short smBh[128 * 64];
  __shared__ alignas(16) short smBl[128 * 64];

  const int tid  = threadIdx.x;
  const int lane = tid & 63;
  const int quad = lane >> 4;
  const int l15  = lane & 15;
  const int wv   = tid >> 6;
  const int wm   = wv & 1;
  const int wn   = wv >> 1;

  const size_t r0 = (size_t)blockIdx.x * 128;
  const int    d0 = blockIdx.y * 128;

  int srow[4], sg8[4];
#pragma unroll
  for (int j = 0; j < 4; ++j) {
    int gi  = j * 256 + tid;
    srow[j] = gi >> 3;
    sg8[j]  = ((gi & 7) ^ (srow[j] & 7)) * 8;
  }

  const unsigned short* ab  = spikes + r0 * 2048;
  const unsigned short* bhb = w2h + (size_t)d0 * 2048;
  const unsigned short* blb = w2l + (size_t)d0 * 2048;

  f32x4 acc[4][4] = {};

  for (int k0 = 0; k0 < 2048; k0 += 64) {
    __syncthreads();
#pragma unroll
    for (int j = 0; j < 4; ++j) {
      load_lds16(ab  + (size_t)srow[j] * 2048 + k0 + sg8[j],
                 &smA [(j * 256 + tid) * 8]);
      load_lds16(bhb + (size_t)srow[j] * 2048 + k0 + sg8[j],
                 &smBh[(j * 256 + tid) * 8]);
      load_lds16(blb + (size_t)srow[j] * 2048 + k0 + sg8[j],
                 &smBl[(j * 256 + tid) * 8]);
    }
    __syncthreads();

#pragma unroll
    for (int ks = 0; ks < 2; ++ks) {
      short8 af[4], bh[4], bl[4];
#pragma unroll
      for (int mi = 0; mi < 4; ++mi) {
        int m = wm * 64 + mi * 16 + l15;
        af[mi] = ((const short8*)smA)[m * 8 + ((ks * 4 + quad) ^ (m & 7))];
      }
#pragma unroll
      for (int ni = 0; ni < 4; ++ni) {
        int n = wn * 64 + ni * 16 + l15;
        int sl = n * 8 + ((ks * 4 + quad) ^ (n & 7));
        bh[ni] = ((const short8*)smBh)[sl];
        bl[ni] = ((const short8*)smBl)[sl];
      }
#pragma unroll
      for (int mi = 0; mi < 4; ++mi)
#pragma unroll
        for (int ni = 0; ni < 4; ++ni) {
          acc[mi][ni] = __builtin_amdgcn_mfma_f32_16x16x32_bf16(
              af[mi], bh[ni], acc[mi][ni], 0, 0, 0);
          acc[mi][ni] = __builtin_amdgcn_mfma_f32_16x16x32_bf16(
              af[mi], bl[ni], acc[mi][ni], 0, 0, 0);
        }
    }
  }

  float* ob = out + r0 * 512 + d0;
#pragma unroll
  for (int mi = 0; mi < 4; ++mi)
#pragma unroll
    for (int ni = 0; ni < 4; ++ni)
#pragma unroll
      for (int r = 0; r < 4; ++r) {
        int rr = wm * 64 + mi * 16 + quad * 4 + r;
        int cc = wn * 64 + ni * 16 + l15;
        ob[(size_t)rr * 512 + cc] = acc[mi][ni][r];
      }
}

// ---------------------------------------------------------------------------
// K2 fallback (no extra ws): out = spikes @ w2^T, fp32 VALU. Grid (256, 8).
// ---------------------------------------------------------------------------
#define KT 16
#define PADF 68

__global__ __launch_bounds__(256) void k2_gemm_valu(
    const unsigned short* __restrict__ spikes,
    const float* __restrict__ w2,
    float* __restrict__ out)
{
  __shared__ float sA[KT][PADF];
  __shared__ float sB[KT][PADF];

  const int tid = threadIdx.x;
  const int tx  = tid & 15;
  const int ty  = tid >> 4;
  const int lr  = tid >> 2;
  const int lg  = tid & 3;

  const size_t r0 = (size_t)blockIdx.x * 64;
  const int    d0 = blockIdx.y * 64;

  float acc[4][4];
#pragma unroll
  for (int i = 0; i < 4; ++i)
#pragma unroll
    for (int j = 0; j < 4; ++j) acc[i][j] = 0.0f;

  for (int k0 = 0; k0 < 2048; k0 += KT) {
    __syncthreads();
    ushort4 av = *(const ushort4*)&spikes[(r0 + lr) * 2048 + k0 + lg * 4];
    float4  bv = *(const float4*)&w2[(size_t)(d0 + lr) * 2048 + k0 + lg * 4];
    sA[lg * 4 + 0][lr] = bf2f(av.x); sA[lg * 4 + 1][lr] = bf2f(av.y);
    sA[lg * 4 + 2][lr] = bf2f(av.z); sA[lg * 4 + 3][lr] = bf2f(av.w);
    sB[lg * 4 + 0][lr] = bv.x; sB[lg * 4 + 1][lr] = bv.y;
    sB[lg * 4 + 2][lr] = bv.z; sB[lg * 4 + 3][lr] = bv.w;
    __syncthreads();

#pragma unroll
    for (int k = 0; k < KT; ++k) {
      float4 a4 = *(const float4*)&sA[k][ty * 4];
      float4 b4 = *(const float4*)&sB[k][tx * 4];
      float aa[4] = {a4.x, a4.y, a4.z, a4.w};
      float bb[4] = {b4.x, b4.y, b4.z, b4.w};
#pragma unroll
      for (int i = 0; i < 4; ++i)
#pragma unroll
        for (int j = 0; j < 4; ++j)
          acc[i][j] = __builtin_fmaf(aa[i], bb[j], acc[i][j]);
    }
  }

#pragma unroll
  for (int i = 0; i < 4; ++i) {
    float4 o = make_float4(acc[i][0], acc[i][1], acc[i][2], acc[i][3]);
    *(float4*)&out[(r0 + ty * 4 + i) * 512 + d0 + tx * 4] = o;
  }
}

// ---------------------------------------------------------------------------
// K3: rate = count / 33554432 -> fp32 at d_out[8388608]
// ---------------------------------------------------------------------------
__global__ void k3_rate(const unsigned* __restrict__ cnt, float* __restrict__ dst) {
  dst[0] = (float)((double)(*cnt) / 33554432.0);
}

extern "C" void kernel_launch(void* const* d_in, const int* in_sizes, int n_in,
                              void* d_out, int out_size, void* d_ws, size_t ws_size,
                              hipStream_t stream) {
  const float* x  = (const float*)d_in[0];
  const float* w1 = (const float*)d_in[1];
  const float* w2 = (const float*)d_in[2];
  float* out = (float*)d_out;

  unsigned* cnt = (unsigned*)d_ws;
  unsigned short* spikes = (unsigned short*)((char*)d_ws + 256);
  const size_t SPIKES_B = (size_t)16384 * 2048 * 2;           // 67108864
  unsigned short* w2h = (unsigned short*)((char*)d_ws + 256 + SPIKES_B);
  unsigned short* w2l = w2h + (size_t)512 * 2048;
  const size_t NEED_SPLIT = 256 + SPIKES_B + 2 * (size_t)512 * 2048 * 2;
  float* xT  = (float*)((char*)d_ws + NEED_SPLIT);
  float* w1T = xT + (size_t)512 * 16384;
  const size_t NEED_FULL = NEED_SPLIT + ((size_t)512 * 16384 + 512 * 2048) * 4;

  hipMemsetAsync(d_ws, 0, 256, stream);  // zero the spike counter

  const bool has_split = ws_size >= NEED_SPLIT;
  const bool has_full  = ws_size >= NEED_FULL;

  if (has_full) {
    hipLaunchKernelGGL(k0x_xpose_x,  dim3(512), dim3(256), 0, stream, x, xT);
    hipLaunchKernelGGL(k0w_xpose_w1, dim3(256), dim3(256), 0, stream, w1, w1T);
    hipLaunchKernelGGL(k1_gemm_lif_dma, dim3(128, 16), dim3(256), 0, stream,
                       xT, w1T, spikes, cnt);
  } else {
    hipLaunchKernelGGL(k1_gemm_lif_legacy, dim3(128, 16), dim3(256), 0, stream,
                       x, w1, spikes, cnt);
  }

  if (has_split) {
    hipLaunchKernelGGL(k0_split, dim3(1024), dim3(256), 0, stream, w2, w2h, w2l);
    hipLaunchKernelGGL(k2_gemm_mfma, dim3(128, 4), dim3(256), 0, stream,
                       spikes, w2h, w2l, out);
  } else {
    hipLaunchKernelGGL(k2_gemm_valu, dim3(256, 8), dim3(256), 0, stream,
                       spikes, w2, out);
  }

  hipLaunchKernelGGL(k3_rate, dim3(1), dim3(1), 0, stream, cnt, out + 8388608);
}

// Round 9
// 542.878 us; speedup vs baseline: 10.5919x; 6.4626x over previous
//
#include <hip/hip_runtime.h>
#include <stdint.h>

// ---------------------------------------------------------------------------
// SpikeMLP (all fp32 I/O):
//   h = x @ w1^T            (16384,512)x(2048,512)^T -> (16384,2048)
//   spikes,rate = LIF(h)    scan over t (4 steps, rows grouped (b,t,s))
//   out = spikes @ w2^T     (16384,2048)x(512,2048)^T -> (16384,512)
//
// Numerics contract (DO NOT BREAK):
//   - GEMM1 (k1): per-element f32 sequential FMA over k=0..511 ascending,
//     one accumulator -> bit-exact match of the np reference's h.
//   - LIF: vv = __fmul_rn(0.95f, v); vv = __fadd_rn(vv, h); spike = vv > 1.
//   - GEMM2 is continuous in spikes {0,1} -> MFMA allowed (w2 hi+lo bf16).
//
// Round 16:
//   k1: ROUND-1 KERNEL VERBATIM (best measured 390.4 us, VGPR 56, no spill).
//     DMA-k1 lane closed after 3 strikes (r6/r7/r8): allocator law budget
//     ~256/N for launch_bounds(256,N); the DMA compute+asm structure spills
//     at every N. Sync structure was bit-exact-correct; register demand was
//     the killer.
//   k2: counted-vmcnt double-buffer (the r6-verified 2-barrier schedule,
//     ported to where register pressure is LOW: acc in AGPRs).
//     Old k2: single-buffered, __syncthreads after global_load_lds = full
//     vmcnt(0) drain x32 chunks = exposed DMA latency (k2 ~110us vs 31us
//     LDS floor). New: BK=32, 6x8KB buffers (48KB), 6 loads/thr/chunk,
//     issue(c+1) -> vmcnt(6) -> barrier -> compute(c) -> lgkm(0) -> barrier.
//     vmcnt never drains mid-loop. Swizzle for 4 k-groups/row:
//     slot = g ^ ((row>>1)&3)  (8 bank-spans, 2 lanes/span = conflict-free,
//     bijective per row). quad = old ks*4+quad with ks baked into buffer.
// ---------------------------------------------------------------------------

typedef __attribute__((ext_vector_type(8))) short short8;   // 8 bf16 = 16 B
typedef __attribute__((ext_vector_type(4))) float f32x4;

#define AS1 __attribute__((address_space(1)))
#define AS3 __attribute__((address_space(3)))

__device__ __forceinline__ void load_lds16(const void* g, void* l) {
  __builtin_amdgcn_global_load_lds((const AS1 void*)g, (AS3 void*)l, 16, 0, 0);
}

__device__ __forceinline__ unsigned short f2bf(float f) {
  union { float f; unsigned u; } un; un.f = f;
  unsigned r = un.u + 0x7FFF + ((un.u >> 16) & 1);   // RNE
  return (unsigned short)(r >> 16);
}
__device__ __forceinline__ float bf2f(unsigned short u) {
  union { unsigned u; float f; } un; un.u = ((unsigned)u) << 16; return un.f;
}

// ---------------------------------------------------------------------------
// K0: split w2 (fp32) into bf16 hi + lo.
// ---------------------------------------------------------------------------
__global__ __launch_bounds__(256) void k0_split(
    const float* __restrict__ w2, unsigned short* __restrict__ hi,
    unsigned short* __restrict__ lo)
{
  int i = (blockIdx.x * 256 + threadIdx.x) * 4;
  float4 w = *(const float4*)&w2[i];
  unsigned short h4[4], l4[4];
  float ws[4] = {w.x, w.y, w.z, w.w};
#pragma unroll
  for (int c = 0; c < 4; ++c) {
    unsigned short h = f2bf(ws[c]);
    h4[c] = h;
    l4[c] = f2bf(ws[c] - bf2f(h));
  }
  *(ushort4*)&hi[i] = *(const ushort4*)h4;
  *(ushort4*)&lo[i] = *(const ushort4*)l4;
}

// ---------------------------------------------------------------------------
// K1: fused GEMM1 (f32 seq-FMA, bit-exact) + thread-local LIF epilogue.
// Round-1 kernel verbatim (measured 390.4 us).
// Block tile: 128 rows (4t x 32s, permuted p = sl*4+t) x 128 cols.
// 256 threads, 8x8 micro. Grid (128, 16).
// ---------------------------------------------------------------------------
#define K1KT 16
#define SA_STR 176   // 128 slots + 48 skew; skew = 16*(k>>2)
#define SB_STR 176

__global__ __launch_bounds__(256, 4) void k1_gemm_lif(
    const float* __restrict__ x,          // (16384, 512), row=((b*4+t)*256+s)
    const float* __restrict__ w1,         // (2048, 512)
    unsigned short* __restrict__ spikes,  // (16384, 2048) bf16 {0,1}
    unsigned* __restrict__ cnt_out)
{
  __shared__ float sA[K1KT * SA_STR];   // 11.0 KB
  __shared__ float sB[K1KT * SB_STR];   // 11.0 KB

  const int tid = threadIdx.x;
  const int tx  = tid & 15;    // col group: cols tx*4..+3 and 64+tx*4..+3
  const int ty  = tid >> 4;    // s-pair index: sl = ty*2 + i, i in {0,1}

  const int bx = blockIdx.x;
  const int b  = bx >> 3;
  const int s0 = (bx & 7) * 32;
  const int h0 = blockIdx.y * 128;

  const int kg = tid & 3;      // staging k-group (kg*4 .. +3 within chunk)
  const int u  = tid >> 2;     // staging slot 0..63 (p = u and u+64)

  float acc[8][8];             // acc[m][j], m = i*4 + t
#pragma unroll
  for (int m = 0; m < 8; ++m)
#pragma unroll
    for (int j = 0; j < 8; ++j) acc[m][j] = 0.0f;

  // Staging global sources. p = u (+64): t = p&3 (64%4==0 -> same t), sl=p>>2.
  const size_t growA0 = ((size_t)(b * 4 + (u & 3)) << 8) + s0 + (u >> 2);
  const size_t growA1 = growA0 + 16;                       // p = u+64: sl += 16
  const float* xA0 = x  + growA0 * 512 + kg * 4;
  const float* xA1 = x  + growA1 * 512 + kg * 4;
  const float* wB0 = w1 + (size_t)(h0 + u) * 512 + kg * 4;
  const float* wB1 = w1 + (size_t)(h0 + u + 64) * 512 + kg * 4;

  // Staging LDS destinations: element (p, k=4*kg+c) -> [k*STR + p + 16*kg].
  float* sAw = &sA[(4 * kg) * SA_STR + u + 16 * kg];   // + c*SA_STR + 64*j imm
  float* sBw = &sB[(4 * kg) * SB_STR + u + 16 * kg];

  // Read bases: all per-k offsets are compile-time immediates.
  const float* sAr = &sA[ty * 8];
  const float* sBr = &sB[tx * 4];

  for (int k0 = 0; k0 < 512; k0 += K1KT) {
    // global loads first: no LDS dependency -> overlap prev chunk's compute
    float4 a0v = *(const float4*)(xA0 + k0);
    float4 a1v = *(const float4*)(xA1 + k0);
    float4 b0v = *(const float4*)(wB0 + k0);
    float4 b1v = *(const float4*)(wB1 + k0);

    __syncthreads();  // protect LDS from previous chunk's readers
    {
      float a0s[4] = {a0v.x, a0v.y, a0v.z, a0v.w};
      float a1s[4] = {a1v.x, a1v.y, a1v.z, a1v.w};
      float b0s[4] = {b0v.x, b0v.y, b0v.z, b0v.w};
      float b1s[4] = {b1v.x, b1v.y, b1v.z, b1v.w};
#pragma unroll
      for (int c = 0; c < 4; ++c) {
        sAw[c * SA_STR]      = a0s[c];
        sAw[c * SA_STR + 64] = a1s[c];
        sBw[c * SB_STR]      = b0s[c];
        sBw[c * SB_STR + 64] = b1s[c];
      }
    }
    __syncthreads();

#pragma unroll
    for (int k = 0; k < K1KT; ++k) {
      const int off = k * SA_STR + 16 * (k >> 2);   // compile-time
      float4 va0 = *(const float4*)(sAr + off);      // rows p0..p0+3 (i=0)
      float4 va1 = *(const float4*)(sAr + off + 4);  // rows p0+4..p0+7 (i=1)
      float4 vb0 = *(const float4*)(sBr + off);      // cols tx*4..+3
      float4 vb1 = *(const float4*)(sBr + off + 64); // cols 64+tx*4..+3
      float av[8] = {va0.x, va0.y, va0.z, va0.w, va1.x, va1.y, va1.z, va1.w};
      float bv[8] = {vb0.x, vb0.y, vb0.z, vb0.w, vb1.x, vb1.y, vb1.z, vb1.w};
#pragma unroll
      for (int m = 0; m < 8; ++m)
#pragma unroll
        for (int j = 0; j < 8; ++j)
          acc[m][j] = __builtin_fmaf(av[m], bv[j], acc[m][j]);
    }
  }

  // Epilogue: LIF. Thread owns all 4 t of its 2 s-rows -> local chain.
  unsigned cnt = 0;
#pragma unroll
  for (int i = 0; i < 2; ++i) {
    unsigned short sp[4][8];
#pragma unroll
    for (int j = 0; j < 8; ++j) {
      float v = 0.0f;
#pragma unroll
      for (int t = 0; t < 4; ++t) {
        float vv = __fadd_rn(__fmul_rn(0.95f, v), acc[i * 4 + t][j]);
        bool s = vv > 1.0f;                 // numpy op-for-op
        sp[t][j] = s ? (unsigned short)0x3F80 : (unsigned short)0;
        cnt += s ? 1u : 0u;
        v = s ? 0.0f : vv;
      }
    }
#pragma unroll
    for (int t = 0; t < 4; ++t) {
      size_t grow = ((size_t)(b * 4 + t) << 8) + s0 + ty * 2 + i;
      unsigned short* rowp = spikes + grow * 2048 + h0;
      ushort4 o0, o1;
      o0.x = sp[t][0]; o0.y = sp[t][1]; o0.z = sp[t][2]; o0.w = sp[t][3];
      o1.x = sp[t][4]; o1.y = sp[t][5]; o1.z = sp[t][6]; o1.w = sp[t][7];
      *(ushort4*)&rowp[tx * 4]      = o0;
      *(ushort4*)&rowp[64 + tx * 4] = o1;
    }
  }

  // wave-reduce spike count -> one atomic per wave
#pragma unroll
  for (int off = 32; off; off >>= 1) cnt += __shfl_down(cnt, off);
  if ((tid & 63) == 0) atomicAdd(cnt_out, cnt);
}

// ---------------------------------------------------------------------------
// K2: out = spikes @ (w2_hi + w2_lo)^T via bf16 MFMA, fp32 accum.
// 128x128 tile, BK=32, DOUBLE-buffered with counted vmcnt. Grid (128, 4).
// Swizzle: 4 k-groups/row, slot = g ^ ((row>>1)&3); row parity supplies the
// other span bit -> 8 bank-spans / fragment read, 2 lanes each (free).
// Loop = the r6-verified 2-barrier schedule; vmcnt(6) mid-loop, never 0.
// ---------------------------------------------------------------------------
#define K2_ISSUE(K0, SA, SBH, SBL)                                         \
  do {                                                                     \
    _Pragma("unroll")                                                      \
    for (int j = 0; j < 2; ++j) {                                          \
      load_lds16(ab  + (size_t)srow[j] * 2048 + (K0) + sg8[j],             \
                 (short*)(SA)  + (j * 256 + tid) * 8);                     \
      load_lds16(bhb + (size_t)srow[j] * 2048 + (K0) + sg8[j],             \
                 (short*)(SBH) + (j * 256 + tid) * 8);                     \
      load_lds16(blb + (size_t)srow[j] * 2048 + (K0) + sg8[j],             \
                 (short*)(SBL) + (j * 256 + tid) * 8);                     \
    }                                                                      \
  } while (0)

#define K2_COMPUTE(SA, SBH, SBL)                                           \
  do {                                                                     \
    short8 af[4], bh[4], bl[4];                                            \
    _Pragma("unroll")                                                      \
    for (int mi = 0; mi < 4; ++mi) {                                       \
      int m = wm * 64 + mi * 16 + l15;                                     \
      af[mi] = ((const short8*)(SA))[m * 4 + (quad ^ ((m >> 1) & 3))];     \
    }                                                                      \
    _Pragma("unroll")                                                      \
    for (int ni = 0; ni < 4; ++ni) {                                       \
      int n = wn * 64 + ni * 16 + l15;                                     \
      int sl = n * 4 + (quad ^ ((n >> 1) & 3));                            \
      bh[ni] = ((const short8*)(SBH))[sl];                                 \
      bl[ni] = ((const short8*)(SBL))[sl];                                 \
    }                                                                      \
    _Pragma("unroll")                                                      \
    for (int mi = 0; mi < 4; ++mi)                                         \
      _Pragma("unroll")                                                    \
      for (int ni = 0; ni < 4; ++ni) {                                     \
        acc[mi][ni] = __builtin_amdgcn_mfma_f32_16x16x32_bf16(             \
            af[mi], bh[ni], acc[mi][ni], 0, 0, 0);                         \
        acc[mi][ni] = __builtin_amdgcn_mfma_f32_16x16x32_bf16(             \
            af[mi], bl[ni], acc[mi][ni], 0, 0, 0);                         \
      }                                                                    \
  } while (0)

#define K2_W6B() asm volatile("s_waitcnt vmcnt(6)\ns_barrier" ::: "memory")
#define K2_W0B() asm volatile("s_waitcnt vmcnt(0)\ns_barrier" ::: "memory")
#define K2_LGB() asm volatile("s_waitcnt lgkmcnt(0)\ns_barrier" ::: "memory")

__global__ __launch_bounds__(256, 2) void k2_gemm_mfma(
    const unsigned short* __restrict__ spikes,  // (16384, 2048) bf16
    const unsigned short* __restrict__ w2h,     // (512, 2048) bf16
    const unsigned short* __restrict__ w2l,     // (512, 2048) bf16
    float* __restrict__ out)                    // (16384, 512) fp32
{
  __shared__ alignas(16) short smA0 [128 * 32];   // 8 KB each, 48 KB total
  __shared__ alignas(16) short smBh0[128 * 32];
  __shared__ alignas(16) short smBl0[128 * 32];
  __shared__ alignas(16) short smA1 [128 * 32];
  __shared__ alignas(16) short smBh1[128 * 32];
  __shared__ alignas(16) short smBl1[128 * 32];

  const int tid  = threadIdx.x;
  const int lane = tid & 63;
  const int quad = lane >> 4;
  const int l15  = lane & 15;
  const int wv   = tid >> 6;
  const int wm   = wv & 1;
  const int wn   = wv >> 1;

  const size_t r0 = (size_t)blockIdx.x * 128;
  const int    d0 = blockIdx.y * 128;

  // staging: gi = j*256+tid -> row = gi>>2 (0..127), group g = gi&3.
  // LDS dest is linear (gi*16 B); global src k-group pre-swizzled.
  int srow[2], sg8[2];
#pragma unroll
  for (int j = 0; j < 2; ++j) {
    int gi  = j * 256 + tid;
    srow[j] = gi >> 2;
    sg8[j]  = (((gi & 3) ^ ((srow[j] >> 1) & 3))) * 8;
  }

  const unsigned short* ab  = spikes + r0 * 2048;
  const unsigned short* bhb = w2h + (size_t)d0 * 2048;
  const unsigned short* blb = w2l + (size_t)d0 * 2048;

  f32x4 acc[4][4] = {};

  K2_ISSUE(0, smA0, smBh0, smBl0);

  for (int k0 = 0; k0 < 2048; k0 += 64) {
    // ---- chunk k0 (set 0) ----
    K2_ISSUE(k0 + 32, smA1, smBh1, smBl1);       // k0+32 <= 2016: in range
    K2_W6B();                                     // set0 landed; 6 in flight
    K2_COMPUTE(smA0, smBh0, smBl0);
    K2_LGB();                                     // close set0 reads
    // ---- chunk k0+32 (set 1) ----
    if (k0 < 1984) { K2_ISSUE(k0 + 64, smA0, smBh0, smBl0); K2_W6B(); }
    else           { K2_W0B(); }
    K2_COMPUTE(smA1, smBh1, smBl1);
    if (k0 < 1984) K2_LGB();
  }

  float* ob = out + r0 * 512 + d0;
#pragma unroll
  for (int mi = 0; mi < 4; ++mi)
#pragma unroll
    for (int ni = 0; ni < 4; ++ni)
#pragma unroll
      for (int r = 0; r < 4; ++r) {
        int rr = wm * 64 + mi * 16 + quad * 4 + r;   // C/D: row=quad*4+reg
        int cc = wn * 64 + ni * 16 + l15;            //      col=lane&15
        ob[(size_t)rr * 512 + cc] = acc[mi][ni][r];
      }
}

// ---------------------------------------------------------------------------
// K2 fallback (no extra ws): out = spikes @ w2^T, fp32 VALU. Grid (256, 8).
// ---------------------------------------------------------------------------
#define KT 16
#define PADF 68

__global__ __launch_bounds__(256) void k2_gemm_valu(
    const unsigned short* __restrict__ spikes,
    const float* __restrict__ w2,
    float* __restrict__ out)
{
  __shared__ float sA[KT][PADF];
  __shared__ float sB[KT][PADF];

  const int tid = threadIdx.x;
  const int tx  = tid & 15;
  const int ty  = tid >> 4;
  const int lr  = tid >> 2;
  const int lg  = tid & 3;

  const size_t r0 = (size_t)blockIdx.x * 64;
  const int    d0 = blockIdx.y * 64;

  float acc[4][4];
#pragma unroll
  for (int i = 0; i < 4; ++i)
#pragma unroll
    for (int j = 0; j < 4; ++j) acc[i][j] = 0.0f;

  for (int k0 = 0; k0 < 2048; k0 += KT) {
    __syncthreads();
    ushort4 av = *(const ushort4*)&spikes[(r0 + lr) * 2048 + k0 + lg * 4];
    float4  bv = *(const float4*)&w2[(size_t)(d0 + lr) * 2048 + k0 + lg * 4];
    sA[lg * 4 + 0][lr] = bf2f(av.x); sA[lg * 4 + 1][lr] = bf2f(av.y);
    sA[lg * 4 + 2][lr] = bf2f(av.z); sA[lg * 4 + 3][lr] = bf2f(av.w);
    sB[lg * 4 + 0][lr] = bv.x; sB[lg * 4 + 1][lr] = bv.y;
    sB[lg * 4 + 2][lr] = bv.z; sB[lg * 4 + 3][lr] = bv.w;
    __syncthreads();

#pragma unroll
    for (int k = 0; k < KT; ++k) {
      float4 a4 = *(const float4*)&sA[k][ty * 4];
      float4 b4 = *(const float4*)&sB[k][tx * 4];
      float aa[4] = {a4.x, a4.y, a4.z, a4.w};
      float bb[4] = {b4.x, b4.y, b4.z, b4.w};
#pragma unroll
      for (int i = 0; i < 4; ++i)
#pragma unroll
        for (int j = 0; j < 4; ++j)
          acc[i][j] = __builtin_fmaf(aa[i], bb[j], acc[i][j]);
    }
  }

#pragma unroll
  for (int i = 0; i < 4; ++i) {
    float4 o = make_float4(acc[i][0], acc[i][1], acc[i][2], acc[i][3]);
    *(float4*)&out[(r0 + ty * 4 + i) * 512 + d0 + tx * 4] = o;
  }
}

// ---------------------------------------------------------------------------
// K3: rate = count / 33554432 -> fp32 at d_out[8388608]
// ---------------------------------------------------------------------------
__global__ void k3_rate(const unsigned* __restrict__ cnt, float* __restrict__ dst) {
  dst[0] = (float)((double)(*cnt) / 33554432.0);
}

extern "C" void kernel_launch(void* const* d_in, const int* in_sizes, int n_in,
                              void* d_out, int out_size, void* d_ws, size_t ws_size,
                              hipStream_t stream) {
  const float* x  = (const float*)d_in[0];
  const float* w1 = (const float*)d_in[1];
  const float* w2 = (const float*)d_in[2];
  float* out = (float*)d_out;

  unsigned* cnt = (unsigned*)d_ws;
  unsigned short* spikes = (unsigned short*)((char*)d_ws + 256);
  const size_t SPIKES_B = (size_t)16384 * 2048 * 2;           // 67108864
  unsigned short* w2h = (unsigned short*)((char*)d_ws + 256 + SPIKES_B);
  unsigned short* w2l = w2h + (size_t)512 * 2048;
  const size_t NEED_SPLIT = 256 + SPIKES_B + 2 * (size_t)512 * 2048 * 2;

  hipMemsetAsync(d_ws, 0, 256, stream);  // zero the spike counter

  hipLaunchKernelGGL(k1_gemm_lif, dim3(128, 16), dim3(256), 0, stream,
                     x, w1, spikes, cnt);

  if (ws_size >= NEED_SPLIT) {
    hipLaunchKernelGGL(k0_split, dim3(1024), dim3(256), 0, stream, w2, w2h, w2l);
    hipLaunchKernelGGL(k2_gemm_mfma, dim3(128, 4), dim3(256), 0, stream,
                       spikes, w2h, w2l, out);
  } else {
    hipLaunchKernelGGL(k2_gemm_valu, dim3(256, 8), dim3(256), 0, stream,
                       spikes, w2, out);
  }

  hipLaunchKernelGGL(k3_rate, dim3(1), dim3(1), 0, stream, cnt, out + 8388608);
}

// Round 10
// 535.436 us; speedup vs baseline: 10.7392x; 1.0139x over previous
//
#include <hip/hip_runtime.h>
#include <stdint.h>

// ---------------------------------------------------------------------------
// SpikeMLP (all fp32 I/O):
//   h = x @ w1^T            (16384,512)x(2048,512)^T -> (16384,2048)
//   spikes,rate = LIF(h)    scan over t (4 steps, rows grouped (b,t,s))
//   out = spikes @ w2^T     (16384,2048)x(512,2048)^T -> (16384,512)
//
// Numerics contract (DO NOT BREAK):
//   - GEMM1 (k1): per-element f32 sequential FMA over k=0..511 ascending,
//     one accumulator -> bit-exact match of the np reference's h.
//   - LIF: vv = __fmul_rn(0.95f, v); vv = __fadd_rn(vv, h); spike = vv > 1.
//   - GEMM2 is continuous in spikes {0,1} -> MFMA allowed (w2 hi+lo bf16).
//
// Round 17:
//   k1: round-1 kernel verbatim (390-399 us, VGPR 56, no spill). Settled.
//   k2: 3-DEEP single-barrier counted-vmcnt pipeline.
//     r9 post-mortem: BK=32 2-deep kept TWO barriers/chunk (vmcnt+bar,
//     lgkm+bar) = 2x barrier frequency of r1's BK=64 kernel -> +25 us.
//     r9's fragment/swizzle mapping passed bit-exact; only the schedule
//     changes. New schedule per chunk c:
//       vmcnt(6); s_barrier; issue(c+2 -> S[(c+2)%3]); compute(c, S[c%3]);
//     RAW: own vmcnt(6) + barrier => chunk c landed for all waves.
//     WAR: issue(c+3) rewrites S[c%3] at step c+1, after the step-c+1
//     barrier that all waves reach only once compute(c) is done.
//     1 barrier per 32k (same per-K rate as r1), no lgkm drain, vmcnt
//     never 0 mid-loop, DMA latency window = 2 compute phases.
//     3 sets x 24 KB = 72 KB LDS -> 2 blocks/CU. Triple-unrolled static
//     buffer names (rule #20). Tail: chunk 63 with vmcnt(0).
// ---------------------------------------------------------------------------

typedef __attribute__((ext_vector_type(8))) short short8;   // 8 bf16 = 16 B
typedef __attribute__((ext_vector_type(4))) float f32x4;

#define AS1 __attribute__((address_space(1)))
#define AS3 __attribute__((address_space(3)))

__device__ __forceinline__ void load_lds16(const void* g, void* l) {
  __builtin_amdgcn_global_load_lds((const AS1 void*)g, (AS3 void*)l, 16, 0, 0);
}

__device__ __forceinline__ unsigned short f2bf(float f) {
  union { float f; unsigned u; } un; un.f = f;
  unsigned r = un.u + 0x7FFF + ((un.u >> 16) & 1);   // RNE
  return (unsigned short)(r >> 16);
}
__device__ __forceinline__ float bf2f(unsigned short u) {
  union { unsigned u; float f; } un; un.u = ((unsigned)u) << 16; return un.f;
}

// ---------------------------------------------------------------------------
// K0: split w2 (fp32) into bf16 hi + lo.
// ---------------------------------------------------------------------------
__global__ __launch_bounds__(256) void k0_split(
    const float* __restrict__ w2, unsigned short* __restrict__ hi,
    unsigned short* __restrict__ lo)
{
  int i = (blockIdx.x * 256 + threadIdx.x) * 4;
  float4 w = *(const float4*)&w2[i];
  unsigned short h4[4], l4[4];
  float ws[4] = {w.x, w.y, w.z, w.w};
#pragma unroll
  for (int c = 0; c < 4; ++c) {
    unsigned short h = f2bf(ws[c]);
    h4[c] = h;
    l4[c] = f2bf(ws[c] - bf2f(h));
  }
  *(ushort4*)&hi[i] = *(const ushort4*)h4;
  *(ushort4*)&lo[i] = *(const ushort4*)l4;
}

// ---------------------------------------------------------------------------
// K1: fused GEMM1 (f32 seq-FMA, bit-exact) + thread-local LIF epilogue.
// Round-1 kernel verbatim (measured 390-399 us).
// Block tile: 128 rows (4t x 32s, permuted p = sl*4+t) x 128 cols.
// 256 threads, 8x8 micro. Grid (128, 16).
// ---------------------------------------------------------------------------
#define K1KT 16
#define SA_STR 176   // 128 slots + 48 skew; skew = 16*(k>>2)
#define SB_STR 176

__global__ __launch_bounds__(256, 4) void k1_gemm_lif(
    const float* __restrict__ x,          // (16384, 512), row=((b*4+t)*256+s)
    const float* __restrict__ w1,         // (2048, 512)
    unsigned short* __restrict__ spikes,  // (16384, 2048) bf16 {0,1}
    unsigned* __restrict__ cnt_out)
{
  __shared__ float sA[K1KT * SA_STR];   // 11.0 KB
  __shared__ float sB[K1KT * SB_STR];   // 11.0 KB

  const int tid = threadIdx.x;
  const int tx  = tid & 15;    // col group: cols tx*4..+3 and 64+tx*4..+3
  const int ty  = tid >> 4;    // s-pair index: sl = ty*2 + i, i in {0,1}

  const int bx = blockIdx.x;
  const int b  = bx >> 3;
  const int s0 = (bx & 7) * 32;
  const int h0 = blockIdx.y * 128;

  const int kg = tid & 3;      // staging k-group (kg*4 .. +3 within chunk)
  const int u  = tid >> 2;     // staging slot 0..63 (p = u and u+64)

  float acc[8][8];             // acc[m][j], m = i*4 + t
#pragma unroll
  for (int m = 0; m < 8; ++m)
#pragma unroll
    for (int j = 0; j < 8; ++j) acc[m][j] = 0.0f;

  // Staging global sources. p = u (+64): t = p&3 (64%4==0 -> same t), sl=p>>2.
  const size_t growA0 = ((size_t)(b * 4 + (u & 3)) << 8) + s0 + (u >> 2);
  const size_t growA1 = growA0 + 16;                       // p = u+64: sl += 16
  const float* xA0 = x  + growA0 * 512 + kg * 4;
  const float* xA1 = x  + growA1 * 512 + kg * 4;
  const float* wB0 = w1 + (size_t)(h0 + u) * 512 + kg * 4;
  const float* wB1 = w1 + (size_t)(h0 + u + 64) * 512 + kg * 4;

  // Staging LDS destinations: element (p, k=4*kg+c) -> [k*STR + p + 16*kg].
  float* sAw = &sA[(4 * kg) * SA_STR + u + 16 * kg];   // + c*SA_STR + 64*j imm
  float* sBw = &sB[(4 * kg) * SB_STR + u + 16 * kg];

  // Read bases: all per-k offsets are compile-time immediates.
  const float* sAr = &sA[ty * 8];
  const float* sBr = &sB[tx * 4];

  for (int k0 = 0; k0 < 512; k0 += K1KT) {
    // global loads first: no LDS dependency -> overlap prev chunk's compute
    float4 a0v = *(const float4*)(xA0 + k0);
    float4 a1v = *(const float4*)(xA1 + k0);
    float4 b0v = *(const float4*)(wB0 + k0);
    float4 b1v = *(const float4*)(wB1 + k0);

    __syncthreads();  // protect LDS from previous chunk's readers
    {
      float a0s[4] = {a0v.x, a0v.y, a0v.z, a0v.w};
      float a1s[4] = {a1v.x, a1v.y, a1v.z, a1v.w};
      float b0s[4] = {b0v.x, b0v.y, b0v.z, b0v.w};
      float b1s[4] = {b1v.x, b1v.y, b1v.z, b1v.w};
#pragma unroll
      for (int c = 0; c < 4; ++c) {
        sAw[c * SA_STR]      = a0s[c];
        sAw[c * SA_STR + 64] = a1s[c];
        sBw[c * SB_STR]      = b0s[c];
        sBw[c * SB_STR + 64] = b1s[c];
      }
    }
    __syncthreads();

#pragma unroll
    for (int k = 0; k < K1KT; ++k) {
      const int off = k * SA_STR + 16 * (k >> 2);   // compile-time
      float4 va0 = *(const float4*)(sAr + off);      // rows p0..p0+3 (i=0)
      float4 va1 = *(const float4*)(sAr + off + 4);  // rows p0+4..p0+7 (i=1)
      float4 vb0 = *(const float4*)(sBr + off);      // cols tx*4..+3
      float4 vb1 = *(const float4*)(sBr + off + 64); // cols 64+tx*4..+3
      float av[8] = {va0.x, va0.y, va0.z, va0.w, va1.x, va1.y, va1.z, va1.w};
      float bv[8] = {vb0.x, vb0.y, vb0.z, vb0.w, vb1.x, vb1.y, vb1.z, vb1.w};
#pragma unroll
      for (int m = 0; m < 8; ++m)
#pragma unroll
        for (int j = 0; j < 8; ++j)
          acc[m][j] = __builtin_fmaf(av[m], bv[j], acc[m][j]);
    }
  }

  // Epilogue: LIF. Thread owns all 4 t of its 2 s-rows -> local chain.
  unsigned cnt = 0;
#pragma unroll
  for (int i = 0; i < 2; ++i) {
    unsigned short sp[4][8];
#pragma unroll
    for (int j = 0; j < 8; ++j) {
      float v = 0.0f;
#pragma unroll
      for (int t = 0; t < 4; ++t) {
        float vv = __fadd_rn(__fmul_rn(0.95f, v), acc[i * 4 + t][j]);
        bool s = vv > 1.0f;                 // numpy op-for-op
        sp[t][j] = s ? (unsigned short)0x3F80 : (unsigned short)0;
        cnt += s ? 1u : 0u;
        v = s ? 0.0f : vv;
      }
    }
#pragma unroll
    for (int t = 0; t < 4; ++t) {
      size_t grow = ((size_t)(b * 4 + t) << 8) + s0 + ty * 2 + i;
      unsigned short* rowp = spikes + grow * 2048 + h0;
      ushort4 o0, o1;
      o0.x = sp[t][0]; o0.y = sp[t][1]; o0.z = sp[t][2]; o0.w = sp[t][3];
      o1.x = sp[t][4]; o1.y = sp[t][5]; o1.z = sp[t][6]; o1.w = sp[t][7];
      *(ushort4*)&rowp[tx * 4]      = o0;
      *(ushort4*)&rowp[64 + tx * 4] = o1;
    }
  }

  // wave-reduce spike count -> one atomic per wave
#pragma unroll
  for (int off = 32; off; off >>= 1) cnt += __shfl_down(cnt, off);
  if ((tid & 63) == 0) atomicAdd(cnt_out, cnt);
}

// ---------------------------------------------------------------------------
// K2: out = spikes @ (w2_hi + w2_lo)^T via bf16 MFMA, fp32 accum.
// 128x128 tile, BK=32, 3-DEEP single-barrier pipeline. Grid (128, 4).
// Chunk c -> set S[c%3]. Per chunk: vmcnt(6); barrier; issue(c+2); compute(c).
// Swizzle (r9-verified): k-group slot = g ^ ((row>>1)&3).
// ---------------------------------------------------------------------------
#define K2_ISSUE(K0, SA, SBH, SBL)                                         \
  do {                                                                     \
    _Pragma("unroll")                                                      \
    for (int j = 0; j < 2; ++j) {                                          \
      load_lds16(ab  + (size_t)srow[j] * 2048 + (K0) + sg8[j],             \
                 (short*)(SA)  + (j * 256 + tid) * 8);                     \
      load_lds16(bhb + (size_t)srow[j] * 2048 + (K0) + sg8[j],             \
                 (short*)(SBH) + (j * 256 + tid) * 8);                     \
      load_lds16(blb + (size_t)srow[j] * 2048 + (K0) + sg8[j],             \
                 (short*)(SBL) + (j * 256 + tid) * 8);                     \
    }                                                                      \
  } while (0)

#define K2_COMPUTE(SA, SBH, SBL)                                           \
  do {                                                                     \
    short8 af[4], bh[4], bl[4];                                            \
    _Pragma("unroll")                                                      \
    for (int mi = 0; mi < 4; ++mi) {                                       \
      int m = wm * 64 + mi * 16 + l15;                                     \
      af[mi] = ((const short8*)(SA))[m * 4 + (quad ^ ((m >> 1) & 3))];     \
    }                                                                      \
    _Pragma("unroll")                                                      \
    for (int ni = 0; ni < 4; ++ni) {                                       \
      int n = wn * 64 + ni * 16 + l15;                                     \
      int sl = n * 4 + (quad ^ ((n >> 1) & 3));                            \
      bh[ni] = ((const short8*)(SBH))[sl];                                 \
      bl[ni] = ((const short8*)(SBL))[sl];                                 \
    }                                                                      \
    _Pragma("unroll")                                                      \
    for (int mi = 0; mi < 4; ++mi)                                         \
      _Pragma("unroll")                                                    \
      for (int ni = 0; ni < 4; ++ni) {                                     \
        acc[mi][ni] = __builtin_amdgcn_mfma_f32_16x16x32_bf16(             \
            af[mi], bh[ni], acc[mi][ni], 0, 0, 0);                         \
        acc[mi][ni] = __builtin_amdgcn_mfma_f32_16x16x32_bf16(             \
            af[mi], bl[ni], acc[mi][ni], 0, 0, 0);                         \
      }                                                                    \
  } while (0)

#define K2_W6B() asm volatile("s_waitcnt vmcnt(6)\ns_barrier" ::: "memory")
#define K2_W0B() asm volatile("s_waitcnt vmcnt(0)\ns_barrier" ::: "memory")

__global__ __launch_bounds__(256, 2) void k2_gemm_mfma(
    const unsigned short* __restrict__ spikes,  // (16384, 2048) bf16
    const unsigned short* __restrict__ w2h,     // (512, 2048) bf16
    const unsigned short* __restrict__ w2l,     // (512, 2048) bf16
    float* __restrict__ out)                    // (16384, 512) fp32
{
  __shared__ alignas(16) short smA0 [128 * 32];   // 8 KB each, 72 KB total
  __shared__ alignas(16) short smBh0[128 * 32];
  __shared__ alignas(16) short smBl0[128 * 32];
  __shared__ alignas(16) short smA1 [128 * 32];
  __shared__ alignas(16) short smBh1[128 * 32];
  __shared__ alignas(16) short smBl1[128 * 32];
  __shared__ alignas(16) short smA2 [128 * 32];
  __shared__ alignas(16) short smBh2[128 * 32];
  __shared__ alignas(16) short smBl2[128 * 32];

  const int tid  = threadIdx.x;
  const int lane = tid & 63;
  const int quad = lane >> 4;
  const int l15  = lane & 15;
  const int wv   = tid >> 6;
  const int wm   = wv & 1;
  const int wn   = wv >> 1;

  const size_t r0 = (size_t)blockIdx.x * 128;
  const int    d0 = blockIdx.y * 128;

  // staging: gi = j*256+tid -> row = gi>>2 (0..127), group g = gi&3.
  // LDS dest linear (gi*16 B); global src k-group pre-swizzled.
  int srow[2], sg8[2];
#pragma unroll
  for (int j = 0; j < 2; ++j) {
    int gi  = j * 256 + tid;
    srow[j] = gi >> 2;
    sg8[j]  = (((gi & 3) ^ ((srow[j] >> 1) & 3))) * 8;
  }

  const unsigned short* ab  = spikes + r0 * 2048;
  const unsigned short* bhb = w2h + (size_t)d0 * 2048;
  const unsigned short* blb = w2l + (size_t)d0 * 2048;

  f32x4 acc[4][4] = {};

  // Prologue: chunks 0 (S0) and 1 (S1) in flight.
  K2_ISSUE(0,  smA0, smBh0, smBl0);
  K2_ISSUE(32, smA1, smBh1, smBl1);

  // 64 chunks of 32 k; chunk c lives in S[c%3]. Chunks 0..62 in the triple
  // loop (c = 0,3,...,60), chunk 63 (S0) in the tail.
  for (int c = 0; c < 63; c += 3) {
    const int k = c * 32;

    K2_W6B();                                   // chunk c landed (all waves)
    K2_ISSUE(k + 64, smA2, smBh2, smBl2);       // chunk c+2 -> S2
    K2_COMPUTE(smA0, smBh0, smBl0);             // chunk c

    K2_W6B();                                   // chunk c+1 landed
    K2_ISSUE(k + 96, smA0, smBh0, smBl0);       // chunk c+3 -> S0
    K2_COMPUTE(smA1, smBh1, smBl1);             // chunk c+1

    K2_W6B();                                   // chunk c+2 landed
    if (c < 60) K2_ISSUE(k + 128, smA1, smBh1, smBl1);  // chunk c+4 -> S1
    K2_COMPUTE(smA2, smBh2, smBl2);             // chunk c+2
  }

  // Tail: chunk 63 in S0 (only 6 loads outstanding).
  K2_W0B();
  K2_COMPUTE(smA0, smBh0, smBl0);

  float* ob = out + r0 * 512 + d0;
#pragma unroll
  for (int mi = 0; mi < 4; ++mi)
#pragma unroll
    for (int ni = 0; ni < 4; ++ni)
#pragma unroll
      for (int r = 0; r < 4; ++r) {
        int rr = wm * 64 + mi * 16 + quad * 4 + r;   // C/D: row=quad*4+reg
        int cc = wn * 64 + ni * 16 + l15;            //      col=lane&15
        ob[(size_t)rr * 512 + cc] = acc[mi][ni][r];
      }
}

// ---------------------------------------------------------------------------
// K2 fallback (no extra ws): out = spikes @ w2^T, fp32 VALU. Grid (256, 8).
// ---------------------------------------------------------------------------
#define KT 16
#define PADF 68

__global__ __launch_bounds__(256) void k2_gemm_valu(
    const unsigned short* __restrict__ spikes,
    const float* __restrict__ w2,
    float* __restrict__ out)
{
  __shared__ float sA[KT][PADF];
  __shared__ float sB[KT][PADF];

  const int tid = threadIdx.x;
  const int tx  = tid & 15;
  const int ty  = tid >> 4;
  const int lr  = tid >> 2;
  const int lg  = tid & 3;

  const size_t r0 = (size_t)blockIdx.x * 64;
  const int    d0 = blockIdx.y * 64;

  float acc[4][4];
#pragma unroll
  for (int i = 0; i < 4; ++i)
#pragma unroll
    for (int j = 0; j < 4; ++j) acc[i][j] = 0.0f;

  for (int k0 = 0; k0 < 2048; k0 += KT) {
    __syncthreads();
    ushort4 av = *(const ushort4*)&spikes[(r0 + lr) * 2048 + k0 + lg * 4];
    float4  bv = *(const float4*)&w2[(size_t)(d0 + lr) * 2048 + k0 + lg * 4];
    sA[lg * 4 + 0][lr] = bf2f(av.x); sA[lg * 4 + 1][lr] = bf2f(av.y);
    sA[lg * 4 + 2][lr] = bf2f(av.z); sA[lg * 4 + 3][lr] = bf2f(av.w);
    sB[lg * 4 + 0][lr] = bv.x; sB[lg * 4 + 1][lr] = bv.y;
    sB[lg * 4 + 2][lr] = bv.z; sB[lg * 4 + 3][lr] = bv.w;
    __syncthreads();

#pragma unroll
    for (int k = 0; k < KT; ++k) {
      float4 a4 = *(const float4*)&sA[k][ty * 4];
      float4 b4 = *(const float4*)&sB[k][tx * 4];
      float aa[4] = {a4.x, a4.y, a4.z, a4.w};
      float bb[4] = {b4.x, b4.y, b4.z, b4.w};
#pragma unroll
      for (int i = 0; i < 4; ++i)
#pragma unroll
        for (int j = 0; j < 4; ++j)
          acc[i][j] = __builtin_fmaf(aa[i], bb[j], acc[i][j]);
    }
  }

#pragma unroll
  for (int i = 0; i < 4; ++i) {
    float4 o = make_float4(acc[i][0], acc[i][1], acc[i][2], acc[i][3]);
    *(float4*)&out[(r0 + ty * 4 + i) * 512 + d0 + tx * 4] = o;
  }
}

// ---------------------------------------------------------------------------
// K3: rate = count / 33554432 -> fp32 at d_out[8388608]
// ---------------------------------------------------------------------------
__global__ void k3_rate(const unsigned* __restrict__ cnt, float* __restrict__ dst) {
  dst[0] = (float)((double)(*cnt) / 33554432.0);
}

extern "C" void kernel_launch(void* const* d_in, const int* in_sizes, int n_in,
                              void* d_out, int out_size, void* d_ws, size_t ws_size,
                              hipStream_t stream) {
  const float* x  = (const float*)d_in[0];
  const float* w1 = (const float*)d_in[1];
  const float* w2 = (const float*)d_in[2];
  float* out = (float*)d_out;

  unsigned* cnt = (unsigned*)d_ws;
  unsigned short* spikes = (unsigned short*)((char*)d_ws + 256);
  const size_t SPIKES_B = (size_t)16384 * 2048 * 2;           // 67108864
  unsigned short* w2h = (unsigned short*)((char*)d_ws + 256 + SPIKES_B);
  unsigned short* w2l = w2h + (size_t)512 * 2048;
  const size_t NEED_SPLIT = 256 + SPIKES_B + 2 * (size_t)512 * 2048 * 2;

  hipMemsetAsync(d_ws, 0, 256, stream);  // zero the spike counter

  hipLaunchKernelGGL(k1_gemm_lif, dim3(128, 16), dim3(256), 0, stream,
                     x, w1, spikes, cnt);

  if (ws_size >= NEED_SPLIT) {
    hipLaunchKernelGGL(k0_split, dim3(1024), dim3(256), 0, stream, w2, w2h, w2l);
    hipLaunchKernelGGL(k2_gemm_mfma, dim3(128, 4), dim3(256), 0, stream,
                       spikes, w2h, w2l, out);
  } else {
    hipLaunchKernelGGL(k2_gemm_valu, dim3(256, 8), dim3(256), 0, stream,
                       spikes, w2, out);
  }

  hipLaunchKernelGGL(k3_rate, dim3(1), dim3(1), 0, stream, cnt, out + 8388608);
}